// Round 16
// baseline (725.683 us; speedup 1.0000x reference)
//
#include <hip/hip_runtime.h>
#include <hip/hip_bf16.h>
#include <stdint.h>

#define BB 8
#define CC 512
#define NN 4096
#define QB 64
#define KB 64
#define D4 2048
#define NT (NN / KB)

typedef short bf8 __attribute__((ext_vector_type(8)));
typedef float f32x4 __attribute__((ext_vector_type(4)));

__device__ __forceinline__ uint16_t f2bf(float f) {
  uint32_t u = __builtin_bit_cast(uint32_t, f);
  u = (u + 0x7FFFu + ((u >> 16) & 1u)) >> 16;
  return (uint16_t)u;
}
__device__ __forceinline__ float bf2f(uint16_t u) {
  return __builtin_bit_cast(float, (uint32_t)u << 16);
}

__device__ __forceinline__ void gl_lds16(const void* g, void* l) {
  __builtin_amdgcn_global_load_lds((__attribute__((address_space(1))) void*)g,
                                   (__attribute__((address_space(3))) void*)l, 16, 0, 0);
}

// [B,C,N] fp32 -> [B,N,C] bf16 (optional scale folded in)
__global__ __launch_bounds__(256) void transpose_cast_k(const float* __restrict__ src,
                                                        uint16_t* __restrict__ dst,
                                                        float scale) {
  __shared__ float tile[32][33];
  int b = blockIdx.z;
  int n0 = blockIdx.x * 32, c0 = blockIdx.y * 32;
  int tx = threadIdx.x & 31, ty = threadIdx.x >> 5;
  const float* s = src + ((size_t)b * CC + c0) * NN + n0;
#pragma unroll
  for (int i = 0; i < 4; i++) {
    int c = ty + i * 8;
    tile[tx][c] = s[(size_t)c * NN + tx];
  }
  __syncthreads();
  uint16_t* d = dst + ((size_t)b * NN + n0) * CC + c0;
#pragma unroll
  for (int i = 0; i < 4; i++) {
    int n = ty + i * 8;
    d[(size_t)n * CC + tx] = f2bf(tile[n][tx] * scale);
  }
}

__global__ __launch_bounds__(256) void cast_k(const float* __restrict__ in,
                                              uint16_t* __restrict__ out, int n) {
  int i = (blockIdx.x * 256 + threadIdx.x) * 4;
  if (i >= n) return;
  float4 v = *(const float4*)(in + i);
  ushort4 o;
  o.x = f2bf(v.x); o.y = f2bf(v.y); o.z = f2bf(v.z); o.w = f2bf(v.w);
  *(ushort4*)(out + i) = o;
}

// Pack V [B,C,N] fp32 -> fragment-ordered bf16 (R13-proven): chunk
// (((b*NT+t)*8+w)*2+ks)*4+rt is 1 KB = 64 lanes x 16 B, fully coalesced.
__global__ __launch_bounds__(256) void vpack_k(const float* __restrict__ v,
                                               uint16_t* __restrict__ vp) {
  const int blk = blockIdx.x;             // (b*NT+mt)*8 + w
  const int w = blk & 7, mtb = blk >> 3;
  const int mt = mtb & (NT - 1), b = mtb >> 6;
  const int tid = threadIdx.x;
#pragma unroll
  for (int h = 0; h < 2; h++) {
    const int c = tid + h * 256;          // ks*256+rt*64+l
    const int ks = c >> 8, rt = (c >> 6) & 3, l = c & 63;
    const int llo = l & 15, lhi = l >> 4;
    const float* src = v + ((size_t)b * CC + w * 64 + rt * 16 + llo) * NN + mt * 64 + ks * 32 + lhi * 8;
    const float4 f0 = *(const float4*)src;
    const float4 f1 = *(const float4*)(src + 4);
    ushort4 o0, o1;
    o0.x = f2bf(f0.x); o0.y = f2bf(f0.y); o0.z = f2bf(f0.z); o0.w = f2bf(f0.w);
    o1.x = f2bf(f1.x); o1.y = f2bf(f1.y); o1.z = f2bf(f1.z); o1.w = f2bf(f1.w);
    uint16_t* dst = vp + (size_t)blk * 4096 + ks * 2048 + rt * 512 + l * 8;
    *(ushort4*)dst = o0;
    *(ushort4*)(dst + 4) = o1;
  }
}

// Fused flash-attention + FFN. Depth-2 pipeline (R15) + SP granule-XOR swizzle
// (R13-proven, applied to all S/P access sites) + FFN hidden double-buffer
// (8 slices of 256, GEMM1(s) || GEMM2(s-1), one barrier per phase).
__global__ __launch_bounds__(512) __attribute__((amdgpu_waves_per_eu(2, 2))) void attn_ffn_k(
    const uint16_t* __restrict__ Qt, const uint16_t* __restrict__ Kt,
    const uint16_t* __restrict__ Vp, const uint16_t* __restrict__ W1b,
    const uint16_t* __restrict__ W2b, const float* __restrict__ b1v_,
    const float* __restrict__ b2, const float* __restrict__ gma,
    const float* __restrict__ qry, float* __restrict__ out) {
  __shared__ __attribute__((aligned(16))) uint16_t Ks[2][KB][CC];  // 128 KB dbuf; FFN overlays
  __shared__ __attribute__((aligned(16))) uint16_t SP[3][QB][72];  // 27 KB: S(bf16)->P in place, swizzled
  __shared__ float rsc[3][QB];
  __shared__ float lst[QB];  // total 159744 B -> 1 block/CU

  const int bid = blockIdx.x + gridDim.x * blockIdx.y;
  const int b = bid & 7;          // batch == XCD round-robin
  const int n0 = (bid >> 3) * QB;
  const int tid = threadIdx.x;
  const int lane = tid & 63, wid = tid >> 6;
  const int lhi = lane >> 4, llo = lane & 15;
  const int r7 = llo & 7;

  const int srt = wid >> 1;        // S row-tile (q), waves pair up
  const int sct0 = (wid & 1) * 2;  // S col-tiles (k): sct0, sct0+1

  // Q fragments -> registers (once)
  bf8 qf[16];
  {
    const uint16_t* qsrc = Qt + ((size_t)b * NN + n0 + srt * 16 + llo) * CC + lhi * 8;
#pragma unroll
    for (int kc = 0; kc < 16; kc++) qf[kc] = *(const bf8*)(qsrc + kc * 32);
  }

  // DMA K(0) -> Ks[0]
#pragma unroll
  for (int j = 0; j < 8; j++) {
    const int r = wid * 8 + j;
    gl_lds16(Kt + ((size_t)b * NN + r) * CC + ((lane ^ (r & 7)) << 3), &Ks[0][r][0]);
  }

  const f32x4 vzero = {0.f, 0.f, 0.f, 0.f};
  f32x4 acc[4][4];
#pragma unroll
  for (int i = 0; i < 4; i++)
#pragma unroll
    for (int j = 0; j < 4; j++) acc[i][j] = vzero;

  const uint16_t* vpw = Vp + (size_t)b * ((size_t)NT * 8 * 4096) + wid * 4096 + lane * 8;
  const int srow = tid >> 3, sj = tid & 7;  // softmax mapping: 8 threads/row
  const int sgc = (sj ^ (srow & 7)) << 3;   // swizzled granule col for this thread's S/P slice
  float m_run = -__builtin_inff(), l_run = 0.f;
  bf8 av[2][4];

  auto QK = [&](int kbuf, int sb) {
    const uint16_t* k0row = &Ks[kbuf][sct0 * 16 + llo][0];
    const uint16_t* k1row = &Ks[kbuf][sct0 * 16 + 16 + llo][0];
    f32x4 s0 = vzero, s1 = vzero;
#pragma unroll
    for (int kc = 0; kc < 16; kc++) {
      const int g = ((kc * 4 + lhi) ^ r7) << 3;
      bf8 bk0 = *(const bf8*)(k0row + g);
      bf8 bk1 = *(const bf8*)(k1row + g);
      s0 = __builtin_amdgcn_mfma_f32_16x16x32_bf16(qf[kc], bk0, s0, 0, 0, 0);
      s1 = __builtin_amdgcn_mfma_f32_16x16x32_bf16(qf[kc], bk1, s1, 0, 0, 0);
    }
    const int nr = srt * 16 + lhi * 4;
    const int gb = sct0 * 2 + (llo >> 3);  // original granule of s0's column
    const int el = llo & 7;
#pragma unroll
    for (int r = 0; r < 4; r++) {
      const int row7 = (lhi * 4 + r) & 7;
      SP[sb][nr + r][((gb ^ row7) << 3) + el] = f2bf(s0[r]);
      SP[sb][nr + r][(((gb + 2) ^ row7) << 3) + el] = f2bf(s1[r]);
    }
  };

  auto SOFTMAX = [&](int sb, bool last) {
    const bf8 sv8 = *(const bf8*)&SP[sb][srow][sgc];
    float sv[8];
#pragma unroll
    for (int k2 = 0; k2 < 8; k2++) sv[k2] = bf2f((uint16_t)sv8[k2]);
    float mx = fmaxf(fmaxf(fmaxf(sv[0], sv[1]), fmaxf(sv[2], sv[3])),
                     fmaxf(fmaxf(sv[4], sv[5]), fmaxf(sv[6], sv[7])));
    mx = fmaxf(mx, __shfl_xor(mx, 1, 8));
    mx = fmaxf(mx, __shfl_xor(mx, 2, 8));
    mx = fmaxf(mx, __shfl_xor(mx, 4, 8));
    const float nm = fmaxf(m_run, mx);
    const float rs = __expf(m_run - nm);
    float p[8], psum = 0.f;
#pragma unroll
    for (int k2 = 0; k2 < 8; k2++) {
      p[k2] = __expf(sv[k2] - nm);
      psum += p[k2];
    }
    bf8 pk;
#pragma unroll
    for (int k2 = 0; k2 < 8; k2++) pk[k2] = (short)f2bf(p[k2]);
    *(bf8*)&SP[sb][srow][sgc] = pk;  // in-place S->P, same swizzled slot
    psum += __shfl_xor(psum, 1, 8);
    psum += __shfl_xor(psum, 2, 8);
    psum += __shfl_xor(psum, 4, 8);
    l_run = l_run * rs + psum;
    m_run = nm;
    if (sj == 0) {
      rsc[sb][srow] = rs;
      if (last) lst[srow] = l_run;
    }
  };

  auto PV = [&](int sb) {
    float rsn[4];
#pragma unroll
    for (int nt = 0; nt < 4; nt++) rsn[nt] = rsc[sb][nt * 16 + llo];
#pragma unroll
    for (int rt = 0; rt < 4; rt++)
#pragma unroll
      for (int nt = 0; nt < 4; nt++) acc[rt][nt] *= rsn[nt];
#pragma unroll
    for (int ks = 0; ks < 2; ks++) {
      bf8 bp[4];
#pragma unroll
      for (int nt = 0; nt < 4; nt++)
        bp[nt] = *(const bf8*)&SP[sb][nt * 16 + llo][(((ks * 4 + lhi) ^ r7) << 3)];
#pragma unroll
      for (int rt = 0; rt < 4; rt++)
#pragma unroll
        for (int nt = 0; nt < 4; nt++)
          acc[rt][nt] = __builtin_amdgcn_mfma_f32_16x16x32_bf16(av[ks][rt], bp[nt], acc[rt][nt], 0, 0, 0);
    }
  };

  auto VLOAD = [&](int t) {
    const uint16_t* vt = vpw + (size_t)t * 32768;
#pragma unroll
    for (int ks = 0; ks < 2; ks++)
#pragma unroll
      for (int rt = 0; rt < 4; rt++)
        av[ks][rt] = *(const bf8*)(vt + ks * 2048 + rt * 512);
  };

  auto KDMA = [&](int t, int buf) {
#pragma unroll
    for (int j = 0; j < 8; j++) {
      const int r = wid * 8 + j;
      gl_lds16(Kt + ((size_t)b * NN + t * KB + r) * CC + ((lane ^ (r & 7)) << 3),
               &Ks[buf][r][0]);
    }
  };

  // ---------- depth-2 pipeline, one barrier per phase ----------
  asm volatile("s_waitcnt vmcnt(0)" ::: "memory");
  __builtin_amdgcn_s_barrier();

  // phase 0: QK(0)
  KDMA(1, 1);
  __builtin_amdgcn_s_setprio(1);
  QK(0, 0);
  __builtin_amdgcn_s_setprio(0);
  asm volatile("s_waitcnt vmcnt(0) lgkmcnt(0)" ::: "memory");
  __builtin_amdgcn_s_barrier();

  // phase 1: softmax(0) || QK(1)
  KDMA(2, 0);
  SOFTMAX(0, false);
  __builtin_amdgcn_s_setprio(1);
  QK(1, 1);
  __builtin_amdgcn_s_setprio(0);
  asm volatile("s_waitcnt vmcnt(0) lgkmcnt(0)" ::: "memory");
  __builtin_amdgcn_s_barrier();

  // main: phase t = softmax(t-1) || PV(t-2) || QK(t)
  int sb0 = 2, sb1 = 1, sb2 = 0;
  for (int t = 2; t < NT; t++) {
    VLOAD(t - 2);
    if (t + 1 < NT) KDMA(t + 1, (t + 1) & 1);
    SOFTMAX(sb1, false);
    __builtin_amdgcn_s_setprio(1);
    PV(sb2);
    QK(t & 1, sb0);
    __builtin_amdgcn_s_setprio(0);
    asm volatile("s_waitcnt vmcnt(0) lgkmcnt(0)" ::: "memory");
    __builtin_amdgcn_s_barrier();
    const int tb = sb2; sb2 = sb1; sb1 = sb0; sb0 = tb;
  }

  // phase NT: softmax(NT-1) || PV(NT-2)
  VLOAD(NT - 2);
  SOFTMAX(sb1, true);
  __builtin_amdgcn_s_setprio(1);
  PV(sb2);
  __builtin_amdgcn_s_setprio(0);
  asm volatile("s_waitcnt vmcnt(0) lgkmcnt(0)" ::: "memory");
  __builtin_amdgcn_s_barrier();
  { const int tb = sb2; sb2 = sb1; sb1 = sb0; sb0 = tb; }

  // phase NT+1: PV(NT-1)
  VLOAD(NT - 1);
  __builtin_amdgcn_s_setprio(1);
  PV(sb2);
  __builtin_amdgcn_s_setprio(0);

  __syncthreads();  // all loop LDS traffic done; Ks free for overlays

  float invl[4];
#pragma unroll
  for (int nt = 0; nt < 4; nt++) invl[nt] = 1.0f / lst[nt * 16 + llo];

  // O[n][c] bf16 -> overlay on Ks[0]
  uint16_t(*Old)[CC] = (uint16_t(*)[CC]) & Ks[0][0][0];
#pragma unroll
  for (int rt = 0; rt < 4; rt++)
#pragma unroll
    for (int nt = 0; nt < 4; nt++) {
      ushort4 o4;
      o4.x = f2bf(acc[rt][nt][0] * invl[nt]);
      o4.y = f2bf(acc[rt][nt][1] * invl[nt]);
      o4.z = f2bf(acc[rt][nt][2] * invl[nt]);
      o4.w = f2bf(acc[rt][nt][3] * invl[nt]);
      const int gch = wid * 8 + rt * 2 + (lhi >> 1);
      *(ushort4*)(&Old[nt * 16 + llo][0] + ((gch ^ r7) << 3) + ((lhi & 1) << 2)) = o4;
    }
  asm volatile("s_waitcnt lgkmcnt(0)" ::: "memory");
  __builtin_amdgcn_s_barrier();  // O visible

  // ---- FFN: 8 slices of 256 hidden, H double-buffered (2 x 32 KB in Ks[1]) ----
  uint16_t* Hb0 = &Ks[1][0][0];
  uint16_t* Hb1 = &Ks[1][32][0];
  const float g = gma[0];
  const uint16_t* orow[4];
#pragma unroll
  for (int nt = 0; nt < 4; nt++) orow[nt] = &Old[nt * 16 + llo][0];

  f32x4 facc[4][4];
#pragma unroll
  for (int i = 0; i < 4; i++)
#pragma unroll
    for (int j = 0; j < 4; j++) facc[i][j] = vzero;

  auto FG1 = [&](int sl) {  // GEMM1(sl): H[sl&1] = relu(O.W1^T + b1) slice
    const int dq0 = sl * 256;
    uint16_t* Hw = (sl & 1) ? Hb1 : Hb0;
    f32x4 hacc[2][4];
#pragma unroll
    for (int i = 0; i < 2; i++)
#pragma unroll
      for (int j = 0; j < 4; j++) hacc[i][j] = vzero;
    __builtin_amdgcn_s_setprio(1);
#pragma unroll 2
    for (int kc8 = 0; kc8 < 64; kc8 += 4) {
      bf8 bo[4], aw[2];
      const int gof = ((kc8 + lhi) ^ r7) << 3;
#pragma unroll
      for (int nt = 0; nt < 4; nt++) bo[nt] = *(const bf8*)(orow[nt] + gof);
#pragma unroll
      for (int dt = 0; dt < 2; dt++)
        aw[dt] = *(const bf8*)(W1b + (size_t)(dq0 + wid * 32 + dt * 16 + llo) * CC + (kc8 + lhi) * 8);
#pragma unroll
      for (int dt = 0; dt < 2; dt++)
#pragma unroll
        for (int nt = 0; nt < 4; nt++)
          hacc[dt][nt] = __builtin_amdgcn_mfma_f32_16x16x32_bf16(aw[dt], bo[nt], hacc[dt][nt], 0, 0, 0);
    }
    __builtin_amdgcn_s_setprio(0);
#pragma unroll
    for (int dt = 0; dt < 2; dt++) {
      const float4 b1v = *(const float4*)(b1v_ + dq0 + wid * 32 + dt * 16 + lhi * 4);
#pragma unroll
      for (int nt = 0; nt < 4; nt++) {
        ushort4 h4;
        h4.x = f2bf(fmaxf(hacc[dt][nt][0] + b1v.x, 0.f));
        h4.y = f2bf(fmaxf(hacc[dt][nt][1] + b1v.y, 0.f));
        h4.z = f2bf(fmaxf(hacc[dt][nt][2] + b1v.z, 0.f));
        h4.w = f2bf(fmaxf(hacc[dt][nt][3] + b1v.w, 0.f));
        const int row = nt * 16 + llo;
        const int gch = wid * 4 + dt * 2 + (lhi >> 1);
        *(ushort4*)(Hw + row * 256 + ((gch ^ r7) << 3) + ((lhi & 1) << 2)) = h4;
      }
    }
  };

  auto FG2 = [&](int sl) {  // GEMM2(sl): facc += H[sl&1] . W2^T slice
    const int dq0 = sl * 256;
    const uint16_t* Hr = (sl & 1) ? Hb1 : Hb0;
    __builtin_amdgcn_s_setprio(1);
#pragma unroll 2
    for (int kd8 = 0; kd8 < 32; kd8 += 4) {
      bf8 ah[4], bw[4];
#pragma unroll
      for (int nt = 0; nt < 4; nt++) {
        const int row = nt * 16 + llo;
        ah[nt] = *(const bf8*)(Hr + row * 256 + (((kd8 + lhi) ^ r7) << 3));
      }
#pragma unroll
      for (int ct = 0; ct < 4; ct++)
        bw[ct] = *(const bf8*)(W2b + (size_t)(wid * 64 + ct * 16 + llo) * D4 + dq0 + (kd8 + lhi) * 8);
#pragma unroll
      for (int nt = 0; nt < 4; nt++)
#pragma unroll
        for (int ct = 0; ct < 4; ct++)
          facc[nt][ct] = __builtin_amdgcn_mfma_f32_16x16x32_bf16(ah[nt], bw[ct], facc[nt][ct], 0, 0, 0);
    }
    __builtin_amdgcn_s_setprio(0);
  };

  FG1(0);
  asm volatile("s_waitcnt lgkmcnt(0)" ::: "memory");
  __builtin_amdgcn_s_barrier();
  for (int sl = 1; sl < 8; sl++) {
    FG1(sl);
    FG2(sl - 1);
    asm volatile("s_waitcnt lgkmcnt(0)" ::: "memory");
    __builtin_amdgcn_s_barrier();
  }
  FG2(7);

  // epilogue: out[b,c,n] = (facc + b2[c])*gamma + query  (float4 along n)
#pragma unroll
  for (int nt = 0; nt < 4; nt++) {
    const int n = n0 + nt * 16 + lhi * 4;
#pragma unroll
    for (int ct = 0; ct < 4; ct++) {
      const int c = wid * 64 + ct * 16 + llo;
      const float b2c = b2[c];
      const size_t off = ((size_t)b * CC + c) * NN + n;
      const float4 q4 = *(const float4*)(qry + off);
      float4 o4;
      o4.x = (facc[nt][ct][0] + b2c) * g + q4.x;
      o4.y = (facc[nt][ct][1] + b2c) * g + q4.y;
      o4.z = (facc[nt][ct][2] + b2c) * g + q4.z;
      o4.w = (facc[nt][ct][3] + b2c) * g + q4.w;
      *(float4*)(out + off) = o4;
    }
  }
}

extern "C" void kernel_launch(void* const* d_in, const int* in_sizes, int n_in,
                              void* d_out, int out_size, void* d_ws, size_t ws_size,
                              hipStream_t stream) {
  const float* q = (const float*)d_in[0];
  const float* k = (const float*)d_in[1];
  const float* v = (const float*)d_in[2];
  const float* w1 = (const float*)d_in[3];
  const float* b1 = (const float*)d_in[4];
  const float* w2 = (const float*)d_in[5];
  const float* b2 = (const float*)d_in[6];
  const float* gm = (const float*)d_in[7];
  float* out = (float*)d_out;

  uint16_t* Qt = (uint16_t*)d_ws;                    // [B][N][C] bf16 (pre-scaled)
  uint16_t* Kt = Qt + (size_t)BB * NN * CC;          // [B][N][C] bf16
  uint16_t* Vp = Kt + (size_t)BB * NN * CC;          // fragment-packed V bf16 (32 MB)
  uint16_t* W1b = Vp + (size_t)BB * NN * CC;         // [2048][512] bf16
  uint16_t* W2b = W1b + (size_t)D4 * CC;             // [512][2048] bf16

  dim3 tgrid(NN / 32, CC / 32, BB);
  transpose_cast_k<<<tgrid, 256, 0, stream>>>(q, Qt, 0.044194173824159216f);
  transpose_cast_k<<<tgrid, 256, 0, stream>>>(k, Kt, 1.0f);
  vpack_k<<<BB * NT * 8, 256, 0, stream>>>(v, Vp);
  cast_k<<<(D4 * CC / 4 + 255) / 256, 256, 0, stream>>>(w1, W1b, D4 * CC);
  cast_k<<<(CC * D4 / 4 + 255) / 256, 256, 0, stream>>>(w2, W2b, CC * D4);
  attn_ffn_k<<<dim3(NN / QB, BB), 512, 0, stream>>>(Qt, Kt, Vp, W1b, W2b, b1, b2, gm, q, out);
}

// Round 17
// 721.328 us; speedup vs baseline: 1.0060x; 1.0060x over previous
//
#include <hip/hip_runtime.h>
#include <hip/hip_bf16.h>
#include <stdint.h>

#define BB 8
#define CC 512
#define NN 4096
#define QB 64
#define KB 64
#define D4 2048
#define NT (NN / KB)

typedef short bf8 __attribute__((ext_vector_type(8)));
typedef float f32x4 __attribute__((ext_vector_type(4)));

__device__ __forceinline__ uint16_t f2bf(float f) {
  uint32_t u = __builtin_bit_cast(uint32_t, f);
  u = (u + 0x7FFFu + ((u >> 16) & 1u)) >> 16;
  return (uint16_t)u;
}
__device__ __forceinline__ float bf2f(uint16_t u) {
  return __builtin_bit_cast(float, (uint32_t)u << 16);
}

__device__ __forceinline__ void gl_lds16(const void* g, void* l) {
  __builtin_amdgcn_global_load_lds((__attribute__((address_space(1))) void*)g,
                                   (__attribute__((address_space(3))) void*)l, 16, 0, 0);
}

// [B,C,N] fp32 -> [B,N,C] bf16 (optional scale folded in)
__global__ __launch_bounds__(256) void transpose_cast_k(const float* __restrict__ src,
                                                        uint16_t* __restrict__ dst,
                                                        float scale) {
  __shared__ float tile[32][33];
  int b = blockIdx.z;
  int n0 = blockIdx.x * 32, c0 = blockIdx.y * 32;
  int tx = threadIdx.x & 31, ty = threadIdx.x >> 5;
  const float* s = src + ((size_t)b * CC + c0) * NN + n0;
#pragma unroll
  for (int i = 0; i < 4; i++) {
    int c = ty + i * 8;
    tile[tx][c] = s[(size_t)c * NN + tx];
  }
  __syncthreads();
  uint16_t* d = dst + ((size_t)b * NN + n0) * CC + c0;
#pragma unroll
  for (int i = 0; i < 4; i++) {
    int n = ty + i * 8;
    d[(size_t)n * CC + tx] = f2bf(tile[n][tx] * scale);
  }
}

__global__ __launch_bounds__(256) void cast_k(const float* __restrict__ in,
                                              uint16_t* __restrict__ out, int n) {
  int i = (blockIdx.x * 256 + threadIdx.x) * 4;
  if (i >= n) return;
  float4 v = *(const float4*)(in + i);
  ushort4 o;
  o.x = f2bf(v.x); o.y = f2bf(v.y); o.z = f2bf(v.z); o.w = f2bf(v.w);
  *(ushort4*)(out + i) = o;
}

// Pack V [B,C,N] fp32 -> fragment-ordered bf16 (R13-proven): chunk
// (((b*NT+t)*8+w)*2+ks)*4+rt is 1 KB = 64 lanes x 16 B, fully coalesced.
__global__ __launch_bounds__(256) void vpack_k(const float* __restrict__ v,
                                               uint16_t* __restrict__ vp) {
  const int blk = blockIdx.x;             // (b*NT+mt)*8 + w
  const int w = blk & 7, mtb = blk >> 3;
  const int mt = mtb & (NT - 1), b = mtb >> 6;
  const int tid = threadIdx.x;
#pragma unroll
  for (int h = 0; h < 2; h++) {
    const int c = tid + h * 256;          // ks*256+rt*64+l
    const int ks = c >> 8, rt = (c >> 6) & 3, l = c & 63;
    const int llo = l & 15, lhi = l >> 4;
    const float* src = v + ((size_t)b * CC + w * 64 + rt * 16 + llo) * NN + mt * 64 + ks * 32 + lhi * 8;
    const float4 f0 = *(const float4*)src;
    const float4 f1 = *(const float4*)(src + 4);
    ushort4 o0, o1;
    o0.x = f2bf(f0.x); o0.y = f2bf(f0.y); o0.z = f2bf(f0.z); o0.w = f2bf(f0.w);
    o1.x = f2bf(f1.x); o1.y = f2bf(f1.y); o1.z = f2bf(f1.z); o1.w = f2bf(f1.w);
    uint16_t* dst = vp + (size_t)blk * 4096 + ks * 2048 + rt * 512 + l * 8;
    *(ushort4*)dst = o0;
    *(ushort4*)(dst + 4) = o1;
  }
}

// Fused flash-attention + FFN. Depth-2 pipeline (R15, plain SP indexing) +
// exact defer-rescale (skip acc*=rs when no row got a new max -> rs==1.0
// bit-exactly) + FFN hidden double-buffer (GEMM1(s) || GEMM2(s-1)).
__global__ __launch_bounds__(512) __attribute__((amdgpu_waves_per_eu(2, 2))) void attn_ffn_k(
    const uint16_t* __restrict__ Qt, const uint16_t* __restrict__ Kt,
    const uint16_t* __restrict__ Vp, const uint16_t* __restrict__ W1b,
    const uint16_t* __restrict__ W2b, const float* __restrict__ b1v_,
    const float* __restrict__ b2, const float* __restrict__ gma,
    const float* __restrict__ qry, float* __restrict__ out) {
  __shared__ __attribute__((aligned(16))) uint16_t Ks[2][KB][CC];  // 128 KB dbuf; FFN overlays
  __shared__ __attribute__((aligned(16))) uint16_t SP[3][QB][72];  // 27 KB: S(bf16)->P in place
  __shared__ float rsc[3][QB];
  __shared__ float lst[QB];  // total 159744 B -> 1 block/CU

  const int bid = blockIdx.x + gridDim.x * blockIdx.y;
  const int b = bid & 7;          // batch == XCD round-robin
  const int n0 = (bid >> 3) * QB;
  const int tid = threadIdx.x;
  const int lane = tid & 63, wid = tid >> 6;
  const int lhi = lane >> 4, llo = lane & 15;
  const int r7 = llo & 7;

  const int srt = wid >> 1;        // S row-tile (q), waves pair up
  const int sct0 = (wid & 1) * 2;  // S col-tiles (k): sct0, sct0+1

  // Q fragments -> registers (once)
  bf8 qf[16];
  {
    const uint16_t* qsrc = Qt + ((size_t)b * NN + n0 + srt * 16 + llo) * CC + lhi * 8;
#pragma unroll
    for (int kc = 0; kc < 16; kc++) qf[kc] = *(const bf8*)(qsrc + kc * 32);
  }

  // DMA K(0) -> Ks[0]
#pragma unroll
  for (int j = 0; j < 8; j++) {
    const int r = wid * 8 + j;
    gl_lds16(Kt + ((size_t)b * NN + r) * CC + ((lane ^ (r & 7)) << 3), &Ks[0][r][0]);
  }

  const f32x4 vzero = {0.f, 0.f, 0.f, 0.f};
  f32x4 acc[4][4];
#pragma unroll
  for (int i = 0; i < 4; i++)
#pragma unroll
    for (int j = 0; j < 4; j++) acc[i][j] = vzero;

  const uint16_t* vpw = Vp + (size_t)b * ((size_t)NT * 8 * 4096) + wid * 4096 + lane * 8;
  const int srow = tid >> 3, sj = tid & 7;  // softmax mapping: 8 threads/row
  float m_run = -__builtin_inff(), l_run = 0.f;
  bf8 av[2][4];

  auto QK = [&](int kbuf, int sb) {
    const uint16_t* k0row = &Ks[kbuf][sct0 * 16 + llo][0];
    const uint16_t* k1row = &Ks[kbuf][sct0 * 16 + 16 + llo][0];
    f32x4 s0 = vzero, s1 = vzero;
#pragma unroll
    for (int kc = 0; kc < 16; kc++) {
      const int g = ((kc * 4 + lhi) ^ r7) << 3;
      bf8 bk0 = *(const bf8*)(k0row + g);
      bf8 bk1 = *(const bf8*)(k1row + g);
      s0 = __builtin_amdgcn_mfma_f32_16x16x32_bf16(qf[kc], bk0, s0, 0, 0, 0);
      s1 = __builtin_amdgcn_mfma_f32_16x16x32_bf16(qf[kc], bk1, s1, 0, 0, 0);
    }
    const int n = srt * 16 + lhi * 4;
#pragma unroll
    for (int r = 0; r < 4; r++) {
      SP[sb][n + r][sct0 * 16 + llo] = f2bf(s0[r]);
      SP[sb][n + r][sct0 * 16 + 16 + llo] = f2bf(s1[r]);
    }
  };

  auto SOFTMAX = [&](int sb, bool last) {
    const bf8 sv8 = *(const bf8*)&SP[sb][srow][sj * 8];
    float sv[8];
#pragma unroll
    for (int k2 = 0; k2 < 8; k2++) sv[k2] = bf2f((uint16_t)sv8[k2]);
    float mx = fmaxf(fmaxf(fmaxf(sv[0], sv[1]), fmaxf(sv[2], sv[3])),
                     fmaxf(fmaxf(sv[4], sv[5]), fmaxf(sv[6], sv[7])));
    mx = fmaxf(mx, __shfl_xor(mx, 1, 8));
    mx = fmaxf(mx, __shfl_xor(mx, 2, 8));
    mx = fmaxf(mx, __shfl_xor(mx, 4, 8));
    const float nm = fmaxf(m_run, mx);
    const float rs = __expf(m_run - nm);
    float p[8], psum = 0.f;
#pragma unroll
    for (int k2 = 0; k2 < 8; k2++) {
      p[k2] = __expf(sv[k2] - nm);
      psum += p[k2];
    }
    bf8 pk;
#pragma unroll
    for (int k2 = 0; k2 < 8; k2++) pk[k2] = (short)f2bf(p[k2]);
    *(bf8*)&SP[sb][srow][sj * 8] = pk;  // in-place S->P (R6/R9-validated)
    psum += __shfl_xor(psum, 1, 8);
    psum += __shfl_xor(psum, 2, 8);
    psum += __shfl_xor(psum, 4, 8);
    l_run = l_run * rs + psum;
    m_run = nm;
    if (sj == 0) {
      rsc[sb][srow] = rs;
      if (last) lst[srow] = l_run;
    }
  };

  auto PV = [&](int sb) {
    float rsn[4];
#pragma unroll
    for (int nt = 0; nt < 4; nt++) rsn[nt] = rsc[sb][nt * 16 + llo];
    // exact defer-rescale: rs==1.0f bit-exactly when no new row max; the
    // wave's rsn values cover all 64 rows -> __all is a uniform decision.
    const bool nochg = (rsn[0] == 1.0f) & (rsn[1] == 1.0f) &
                       (rsn[2] == 1.0f) & (rsn[3] == 1.0f);
    if (!__all(nochg)) {
#pragma unroll
      for (int rt = 0; rt < 4; rt++)
#pragma unroll
        for (int nt = 0; nt < 4; nt++) acc[rt][nt] *= rsn[nt];
    }
#pragma unroll
    for (int ks = 0; ks < 2; ks++) {
      bf8 bp[4];
#pragma unroll
      for (int nt = 0; nt < 4; nt++)
        bp[nt] = *(const bf8*)&SP[sb][nt * 16 + llo][(ks * 4 + lhi) * 8];
#pragma unroll
      for (int rt = 0; rt < 4; rt++)
#pragma unroll
        for (int nt = 0; nt < 4; nt++)
          acc[rt][nt] = __builtin_amdgcn_mfma_f32_16x16x32_bf16(av[ks][rt], bp[nt], acc[rt][nt], 0, 0, 0);
    }
  };

  auto VLOAD = [&](int t) {
    const uint16_t* vt = vpw + (size_t)t * 32768;
#pragma unroll
    for (int ks = 0; ks < 2; ks++)
#pragma unroll
      for (int rt = 0; rt < 4; rt++)
        av[ks][rt] = *(const bf8*)(vt + ks * 2048 + rt * 512);
  };

  auto KDMA = [&](int t, int buf) {
#pragma unroll
    for (int j = 0; j < 8; j++) {
      const int r = wid * 8 + j;
      gl_lds16(Kt + ((size_t)b * NN + t * KB + r) * CC + ((lane ^ (r & 7)) << 3),
               &Ks[buf][r][0]);
    }
  };

  // ---------- depth-2 pipeline, one barrier per phase ----------
  asm volatile("s_waitcnt vmcnt(0)" ::: "memory");
  __builtin_amdgcn_s_barrier();

  // phase 0: QK(0)
  KDMA(1, 1);
  __builtin_amdgcn_s_setprio(1);
  QK(0, 0);
  __builtin_amdgcn_s_setprio(0);
  asm volatile("s_waitcnt vmcnt(0) lgkmcnt(0)" ::: "memory");
  __builtin_amdgcn_s_barrier();

  // phase 1: softmax(0) || QK(1)
  KDMA(2, 0);
  SOFTMAX(0, false);
  __builtin_amdgcn_s_setprio(1);
  QK(1, 1);
  __builtin_amdgcn_s_setprio(0);
  asm volatile("s_waitcnt vmcnt(0) lgkmcnt(0)" ::: "memory");
  __builtin_amdgcn_s_barrier();

  // main: phase t = softmax(t-1) || PV(t-2) || QK(t)
  int sb0 = 2, sb1 = 1, sb2 = 0;
  for (int t = 2; t < NT; t++) {
    VLOAD(t - 2);
    if (t + 1 < NT) KDMA(t + 1, (t + 1) & 1);
    SOFTMAX(sb1, false);
    __builtin_amdgcn_s_setprio(1);
    PV(sb2);
    QK(t & 1, sb0);
    __builtin_amdgcn_s_setprio(0);
    asm volatile("s_waitcnt vmcnt(0) lgkmcnt(0)" ::: "memory");
    __builtin_amdgcn_s_barrier();
    const int tb = sb2; sb2 = sb1; sb1 = sb0; sb0 = tb;
  }

  // phase NT: softmax(NT-1) || PV(NT-2)
  VLOAD(NT - 2);
  SOFTMAX(sb1, true);
  __builtin_amdgcn_s_setprio(1);
  PV(sb2);
  __builtin_amdgcn_s_setprio(0);
  asm volatile("s_waitcnt vmcnt(0) lgkmcnt(0)" ::: "memory");
  __builtin_amdgcn_s_barrier();
  { const int tb = sb2; sb2 = sb1; sb1 = sb0; sb0 = tb; }

  // phase NT+1: PV(NT-1)
  VLOAD(NT - 1);
  __builtin_amdgcn_s_setprio(1);
  PV(sb2);
  __builtin_amdgcn_s_setprio(0);

  __syncthreads();  // all loop LDS traffic done; Ks free for overlays

  float invl[4];
#pragma unroll
  for (int nt = 0; nt < 4; nt++) invl[nt] = 1.0f / lst[nt * 16 + llo];

  // O[n][c] bf16 -> overlay on Ks[0]
  uint16_t(*Old)[CC] = (uint16_t(*)[CC]) & Ks[0][0][0];
#pragma unroll
  for (int rt = 0; rt < 4; rt++)
#pragma unroll
    for (int nt = 0; nt < 4; nt++) {
      ushort4 o4;
      o4.x = f2bf(acc[rt][nt][0] * invl[nt]);
      o4.y = f2bf(acc[rt][nt][1] * invl[nt]);
      o4.z = f2bf(acc[rt][nt][2] * invl[nt]);
      o4.w = f2bf(acc[rt][nt][3] * invl[nt]);
      const int gch = wid * 8 + rt * 2 + (lhi >> 1);
      *(ushort4*)(&Old[nt * 16 + llo][0] + ((gch ^ r7) << 3) + ((lhi & 1) << 2)) = o4;
    }
  asm volatile("s_waitcnt lgkmcnt(0)" ::: "memory");
  __builtin_amdgcn_s_barrier();  // O visible

  // ---- FFN: 8 slices of 256 hidden, H double-buffered (2 x 32 KB in Ks[1]) ----
  uint16_t* Hb0 = &Ks[1][0][0];
  uint16_t* Hb1 = &Ks[1][32][0];
  const float g = gma[0];
  const uint16_t* orow[4];
#pragma unroll
  for (int nt = 0; nt < 4; nt++) orow[nt] = &Old[nt * 16 + llo][0];

  f32x4 facc[4][4];
#pragma unroll
  for (int i = 0; i < 4; i++)
#pragma unroll
    for (int j = 0; j < 4; j++) facc[i][j] = vzero;

  auto FG1 = [&](int sl) {  // GEMM1(sl): H[sl&1] = relu(O.W1^T + b1) slice
    const int dq0 = sl * 256;
    uint16_t* Hw = (sl & 1) ? Hb1 : Hb0;
    f32x4 hacc[2][4];
#pragma unroll
    for (int i = 0; i < 2; i++)
#pragma unroll
      for (int j = 0; j < 4; j++) hacc[i][j] = vzero;
    __builtin_amdgcn_s_setprio(1);
#pragma unroll 2
    for (int kc8 = 0; kc8 < 64; kc8 += 4) {
      bf8 bo[4], aw[2];
      const int gof = ((kc8 + lhi) ^ r7) << 3;
#pragma unroll
      for (int nt = 0; nt < 4; nt++) bo[nt] = *(const bf8*)(orow[nt] + gof);
#pragma unroll
      for (int dt = 0; dt < 2; dt++)
        aw[dt] = *(const bf8*)(W1b + (size_t)(dq0 + wid * 32 + dt * 16 + llo) * CC + (kc8 + lhi) * 8);
#pragma unroll
      for (int dt = 0; dt < 2; dt++)
#pragma unroll
        for (int nt = 0; nt < 4; nt++)
          hacc[dt][nt] = __builtin_amdgcn_mfma_f32_16x16x32_bf16(aw[dt], bo[nt], hacc[dt][nt], 0, 0, 0);
    }
    __builtin_amdgcn_s_setprio(0);
#pragma unroll
    for (int dt = 0; dt < 2; dt++) {
      const float4 b1v = *(const float4*)(b1v_ + dq0 + wid * 32 + dt * 16 + lhi * 4);
#pragma unroll
      for (int nt = 0; nt < 4; nt++) {
        ushort4 h4;
        h4.x = f2bf(fmaxf(hacc[dt][nt][0] + b1v.x, 0.f));
        h4.y = f2bf(fmaxf(hacc[dt][nt][1] + b1v.y, 0.f));
        h4.z = f2bf(fmaxf(hacc[dt][nt][2] + b1v.z, 0.f));
        h4.w = f2bf(fmaxf(hacc[dt][nt][3] + b1v.w, 0.f));
        const int row = nt * 16 + llo;
        const int gch = wid * 4 + dt * 2 + (lhi >> 1);
        *(ushort4*)(Hw + row * 256 + ((gch ^ r7) << 3) + ((lhi & 1) << 2)) = h4;
      }
    }
  };

  auto FG2 = [&](int sl) {  // GEMM2(sl): facc += H[sl&1] . W2^T slice
    const int dq0 = sl * 256;
    const uint16_t* Hr = (sl & 1) ? Hb1 : Hb0;
    __builtin_amdgcn_s_setprio(1);
#pragma unroll 2
    for (int kd8 = 0; kd8 < 32; kd8 += 4) {
      bf8 ah[4], bw[4];
#pragma unroll
      for (int nt = 0; nt < 4; nt++) {
        const int row = nt * 16 + llo;
        ah[nt] = *(const bf8*)(Hr + row * 256 + (((kd8 + lhi) ^ r7) << 3));
      }
#pragma unroll
      for (int ct = 0; ct < 4; ct++)
        bw[ct] = *(const bf8*)(W2b + (size_t)(wid * 64 + ct * 16 + llo) * D4 + dq0 + (kd8 + lhi) * 8);
#pragma unroll
      for (int nt = 0; nt < 4; nt++)
#pragma unroll
        for (int ct = 0; ct < 4; ct++)
          facc[nt][ct] = __builtin_amdgcn_mfma_f32_16x16x32_bf16(ah[nt], bw[ct], facc[nt][ct], 0, 0, 0);
    }
    __builtin_amdgcn_s_setprio(0);
  };

  FG1(0);
  asm volatile("s_waitcnt lgkmcnt(0)" ::: "memory");
  __builtin_amdgcn_s_barrier();
  for (int sl = 1; sl < 8; sl++) {
    FG1(sl);
    FG2(sl - 1);
    asm volatile("s_waitcnt lgkmcnt(0)" ::: "memory");
    __builtin_amdgcn_s_barrier();
  }
  FG2(7);

  // epilogue: out[b,c,n] = (facc + b2[c])*gamma + query  (float4 along n)
#pragma unroll
  for (int nt = 0; nt < 4; nt++) {
    const int n = n0 + nt * 16 + lhi * 4;
#pragma unroll
    for (int ct = 0; ct < 4; ct++) {
      const int c = wid * 64 + ct * 16 + llo;
      const float b2c = b2[c];
      const size_t off = ((size_t)b * CC + c) * NN + n;
      const float4 q4 = *(const float4*)(qry + off);
      float4 o4;
      o4.x = (facc[nt][ct][0] + b2c) * g + q4.x;
      o4.y = (facc[nt][ct][1] + b2c) * g + q4.y;
      o4.z = (facc[nt][ct][2] + b2c) * g + q4.z;
      o4.w = (facc[nt][ct][3] + b2c) * g + q4.w;
      *(float4*)(out + off) = o4;
    }
  }
}

extern "C" void kernel_launch(void* const* d_in, const int* in_sizes, int n_in,
                              void* d_out, int out_size, void* d_ws, size_t ws_size,
                              hipStream_t stream) {
  const float* q = (const float*)d_in[0];
  const float* k = (const float*)d_in[1];
  const float* v = (const float*)d_in[2];
  const float* w1 = (const float*)d_in[3];
  const float* b1 = (const float*)d_in[4];
  const float* w2 = (const float*)d_in[5];
  const float* b2 = (const float*)d_in[6];
  const float* gm = (const float*)d_in[7];
  float* out = (float*)d_out;

  uint16_t* Qt = (uint16_t*)d_ws;                    // [B][N][C] bf16 (pre-scaled)
  uint16_t* Kt = Qt + (size_t)BB * NN * CC;          // [B][N][C] bf16
  uint16_t* Vp = Kt + (size_t)BB * NN * CC;          // fragment-packed V bf16 (32 MB)
  uint16_t* W1b = Vp + (size_t)BB * NN * CC;         // [2048][512] bf16
  uint16_t* W2b = W1b + (size_t)D4 * CC;             // [512][2048] bf16

  dim3 tgrid(NN / 32, CC / 32, BB);
  transpose_cast_k<<<tgrid, 256, 0, stream>>>(q, Qt, 0.044194173824159216f);
  transpose_cast_k<<<tgrid, 256, 0, stream>>>(k, Kt, 1.0f);
  vpack_k<<<BB * NT * 8, 256, 0, stream>>>(v, Vp);
  cast_k<<<(D4 * CC / 4 + 255) / 256, 256, 0, stream>>>(w1, W1b, D4 * CC);
  cast_k<<<(CC * D4 / 4 + 255) / 256, 256, 0, stream>>>(w2, W2b, CC * D4);
  attn_ffn_k<<<dim3(NN / QB, BB), 512, 0, stream>>>(Qt, Kt, Vp, W1b, W2b, b1, b2, gm, q, out);
}

// Round 18
// 704.993 us; speedup vs baseline: 1.0293x; 1.0232x over previous
//
#include <hip/hip_runtime.h>
#include <hip/hip_bf16.h>
#include <stdint.h>

#define BB 8
#define CC 512
#define NN 4096
#define QB 64
#define KB 64
#define D4 2048
#define NT (NN / KB)
#define SPAD 80  // SP row stride (u16): 160 B = 40 dwords == 8 mod 32 -> uniform b128 bank starts

typedef short bf8 __attribute__((ext_vector_type(8)));
typedef float f32x4 __attribute__((ext_vector_type(4)));

__device__ __forceinline__ uint16_t f2bf(float f) {
  uint32_t u = __builtin_bit_cast(uint32_t, f);
  u = (u + 0x7FFFu + ((u >> 16) & 1u)) >> 16;
  return (uint16_t)u;
}
__device__ __forceinline__ float bf2f(uint16_t u) {
  return __builtin_bit_cast(float, (uint32_t)u << 16);
}

__device__ __forceinline__ void gl_lds16(const void* g, void* l) {
  __builtin_amdgcn_global_load_lds((__attribute__((address_space(1))) void*)g,
                                   (__attribute__((address_space(3))) void*)l, 16, 0, 0);
}

// [B,C,N] fp32 -> [B,N,C] bf16 (optional scale folded in)
__global__ __launch_bounds__(256) void transpose_cast_k(const float* __restrict__ src,
                                                        uint16_t* __restrict__ dst,
                                                        float scale) {
  __shared__ float tile[32][33];
  int b = blockIdx.z;
  int n0 = blockIdx.x * 32, c0 = blockIdx.y * 32;
  int tx = threadIdx.x & 31, ty = threadIdx.x >> 5;
  const float* s = src + ((size_t)b * CC + c0) * NN + n0;
#pragma unroll
  for (int i = 0; i < 4; i++) {
    int c = ty + i * 8;
    tile[tx][c] = s[(size_t)c * NN + tx];
  }
  __syncthreads();
  uint16_t* d = dst + ((size_t)b * NN + n0) * CC + c0;
#pragma unroll
  for (int i = 0; i < 4; i++) {
    int n = ty + i * 8;
    d[(size_t)n * CC + tx] = f2bf(tile[n][tx] * scale);
  }
}

__global__ __launch_bounds__(256) void cast_k(const float* __restrict__ in,
                                              uint16_t* __restrict__ out, int n) {
  int i = (blockIdx.x * 256 + threadIdx.x) * 4;
  if (i >= n) return;
  float4 v = *(const float4*)(in + i);
  ushort4 o;
  o.x = f2bf(v.x); o.y = f2bf(v.y); o.z = f2bf(v.z); o.w = f2bf(v.w);
  *(ushort4*)(out + i) = o;
}

// Pack V [B,C,N] fp32 -> fragment-ordered bf16 (R13-proven): chunk
// (((b*NT+t)*8+w)*2+ks)*4+rt is 1 KB = 64 lanes x 16 B, fully coalesced.
__global__ __launch_bounds__(256) void vpack_k(const float* __restrict__ v,
                                               uint16_t* __restrict__ vp) {
  const int blk = blockIdx.x;             // (b*NT+mt)*8 + w
  const int w = blk & 7, mtb = blk >> 3;
  const int mt = mtb & (NT - 1), b = mtb >> 6;
  const int tid = threadIdx.x;
#pragma unroll
  for (int h = 0; h < 2; h++) {
    const int c = tid + h * 256;          // ks*256+rt*64+l
    const int ks = c >> 8, rt = (c >> 6) & 3, l = c & 63;
    const int llo = l & 15, lhi = l >> 4;
    const float* src = v + ((size_t)b * CC + w * 64 + rt * 16 + llo) * NN + mt * 64 + ks * 32 + lhi * 8;
    const float4 f0 = *(const float4*)src;
    const float4 f1 = *(const float4*)(src + 4);
    ushort4 o0, o1;
    o0.x = f2bf(f0.x); o0.y = f2bf(f0.y); o0.z = f2bf(f0.z); o0.w = f2bf(f0.w);
    o1.x = f2bf(f1.x); o1.y = f2bf(f1.y); o1.z = f2bf(f1.z); o1.w = f2bf(f1.w);
    uint16_t* dst = vp + (size_t)blk * 4096 + ks * 2048 + rt * 512 + l * 8;
    *(ushort4*)dst = o0;
    *(ushort4*)(dst + 4) = o1;
  }
}

// Fused flash-attention + FFN. Depth-2 pipeline (R15), ONE barrier/iter:
//   phase(t): VLOAD(t-2) + KDMA(t+1)  [VMEM]
//          || softmax(t-1)            [VALU, SP[sb1] in-place S->P]
//          || PV(t-2) + QK(t)         [MFMA: SP[sb2] read, SP[sb0] write]
// SP row stride = 80 u16 (dword residue 8 mod 32): uniform quad-bank starts
// for all b128 SP accesses -> bank-conflict-free softmax/PV paths.
__global__ __launch_bounds__(512) __attribute__((amdgpu_waves_per_eu(2, 2))) void attn_ffn_k(
    const uint16_t* __restrict__ Qt, const uint16_t* __restrict__ Kt,
    const uint16_t* __restrict__ Vp, const uint16_t* __restrict__ W1b,
    const uint16_t* __restrict__ W2b, const float* __restrict__ b1v_,
    const float* __restrict__ b2, const float* __restrict__ gma,
    const float* __restrict__ qry, float* __restrict__ out) {
  __shared__ __attribute__((aligned(16))) uint16_t Ks[2][KB][CC];   // 128 KB dbuf; FFN overlay
  __shared__ __attribute__((aligned(16))) uint16_t SP[3][QB][SPAD]; // 30 KB: S(bf16)->P in place
  __shared__ float rsc[3][QB];
  __shared__ float lst[QB];  // total 162816 B -> 1 block/CU

  const int bid = blockIdx.x + gridDim.x * blockIdx.y;
  const int b = bid & 7;          // batch == XCD round-robin
  const int n0 = (bid >> 3) * QB;
  const int tid = threadIdx.x;
  const int lane = tid & 63, wid = tid >> 6;
  const int lhi = lane >> 4, llo = lane & 15;
  const int r7 = llo & 7;

  const int srt = wid >> 1;        // S row-tile (q), waves pair up
  const int sct0 = (wid & 1) * 2;  // S col-tiles (k): sct0, sct0+1

  // Q fragments -> registers (once)
  bf8 qf[16];
  {
    const uint16_t* qsrc = Qt + ((size_t)b * NN + n0 + srt * 16 + llo) * CC + lhi * 8;
#pragma unroll
    for (int kc = 0; kc < 16; kc++) qf[kc] = *(const bf8*)(qsrc + kc * 32);
  }

  // DMA K(0) -> Ks[0]
#pragma unroll
  for (int j = 0; j < 8; j++) {
    const int r = wid * 8 + j;
    gl_lds16(Kt + ((size_t)b * NN + r) * CC + ((lane ^ (r & 7)) << 3), &Ks[0][r][0]);
  }

  const f32x4 vzero = {0.f, 0.f, 0.f, 0.f};
  f32x4 acc[4][4];
#pragma unroll
  for (int i = 0; i < 4; i++)
#pragma unroll
    for (int j = 0; j < 4; j++) acc[i][j] = vzero;

  const uint16_t* vpw = Vp + (size_t)b * ((size_t)NT * 8 * 4096) + wid * 4096 + lane * 8;
  const int srow = tid >> 3, sj = tid & 7;  // softmax mapping: 8 threads/row
  float m_run = -__builtin_inff(), l_run = 0.f;
  bf8 av[2][4];

  auto QK = [&](int kbuf, int sb) {
    const uint16_t* k0row = &Ks[kbuf][sct0 * 16 + llo][0];
    const uint16_t* k1row = &Ks[kbuf][sct0 * 16 + 16 + llo][0];
    f32x4 s0 = vzero, s1 = vzero;
#pragma unroll
    for (int kc = 0; kc < 16; kc++) {
      const int g = ((kc * 4 + lhi) ^ r7) << 3;
      bf8 bk0 = *(const bf8*)(k0row + g);
      bf8 bk1 = *(const bf8*)(k1row + g);
      s0 = __builtin_amdgcn_mfma_f32_16x16x32_bf16(qf[kc], bk0, s0, 0, 0, 0);
      s1 = __builtin_amdgcn_mfma_f32_16x16x32_bf16(qf[kc], bk1, s1, 0, 0, 0);
    }
    const int n = srt * 16 + lhi * 4;
#pragma unroll
    for (int r = 0; r < 4; r++) {
      SP[sb][n + r][sct0 * 16 + llo] = f2bf(s0[r]);
      SP[sb][n + r][sct0 * 16 + 16 + llo] = f2bf(s1[r]);
    }
  };

  auto SOFTMAX = [&](int sb, bool last) {
    const bf8 sv8 = *(const bf8*)&SP[sb][srow][sj * 8];
    float sv[8];
#pragma unroll
    for (int k2 = 0; k2 < 8; k2++) sv[k2] = bf2f((uint16_t)sv8[k2]);
    float mx = fmaxf(fmaxf(fmaxf(sv[0], sv[1]), fmaxf(sv[2], sv[3])),
                     fmaxf(fmaxf(sv[4], sv[5]), fmaxf(sv[6], sv[7])));
    mx = fmaxf(mx, __shfl_xor(mx, 1, 8));
    mx = fmaxf(mx, __shfl_xor(mx, 2, 8));
    mx = fmaxf(mx, __shfl_xor(mx, 4, 8));
    const float nm = fmaxf(m_run, mx);
    const float rs = __expf(m_run - nm);
    float p[8], psum = 0.f;
#pragma unroll
    for (int k2 = 0; k2 < 8; k2++) {
      p[k2] = __expf(sv[k2] - nm);
      psum += p[k2];
    }
    bf8 pk;
#pragma unroll
    for (int k2 = 0; k2 < 8; k2++) pk[k2] = (short)f2bf(p[k2]);
    *(bf8*)&SP[sb][srow][sj * 8] = pk;  // in-place S->P (R6/R9-validated)
    psum += __shfl_xor(psum, 1, 8);
    psum += __shfl_xor(psum, 2, 8);
    psum += __shfl_xor(psum, 4, 8);
    l_run = l_run * rs + psum;
    m_run = nm;
    if (sj == 0) {
      rsc[sb][srow] = rs;
      if (last) lst[srow] = l_run;
    }
  };

  auto PV = [&](int sb) {
    float rsn[4];
#pragma unroll
    for (int nt = 0; nt < 4; nt++) rsn[nt] = rsc[sb][nt * 16 + llo];
#pragma unroll
    for (int rt = 0; rt < 4; rt++)
#pragma unroll
      for (int nt = 0; nt < 4; nt++) acc[rt][nt] *= rsn[nt];
#pragma unroll
    for (int ks = 0; ks < 2; ks++) {
      bf8 bp[4];
#pragma unroll
      for (int nt = 0; nt < 4; nt++)
        bp[nt] = *(const bf8*)&SP[sb][nt * 16 + llo][(ks * 4 + lhi) * 8];
#pragma unroll
      for (int rt = 0; rt < 4; rt++)
#pragma unroll
        for (int nt = 0; nt < 4; nt++)
          acc[rt][nt] = __builtin_amdgcn_mfma_f32_16x16x32_bf16(av[ks][rt], bp[nt], acc[rt][nt], 0, 0, 0);
    }
  };

  auto VLOAD = [&](int t) {
    const uint16_t* vt = vpw + (size_t)t * 32768;
#pragma unroll
    for (int ks = 0; ks < 2; ks++)
#pragma unroll
      for (int rt = 0; rt < 4; rt++)
        av[ks][rt] = *(const bf8*)(vt + ks * 2048 + rt * 512);
  };

  auto KDMA = [&](int t, int buf) {
#pragma unroll
    for (int j = 0; j < 8; j++) {
      const int r = wid * 8 + j;
      gl_lds16(Kt + ((size_t)b * NN + t * KB + r) * CC + ((lane ^ (r & 7)) << 3),
               &Ks[buf][r][0]);
    }
  };

  // ---------- depth-2 pipeline, one barrier per phase ----------
  asm volatile("s_waitcnt vmcnt(0)" ::: "memory");
  __builtin_amdgcn_s_barrier();

  // phase 0: QK(0)
  KDMA(1, 1);
  __builtin_amdgcn_s_setprio(1);
  QK(0, 0);
  __builtin_amdgcn_s_setprio(0);
  asm volatile("s_waitcnt vmcnt(0) lgkmcnt(0)" ::: "memory");
  __builtin_amdgcn_s_barrier();

  // phase 1: softmax(0) || QK(1)
  KDMA(2, 0);
  SOFTMAX(0, false);
  __builtin_amdgcn_s_setprio(1);
  QK(1, 1);
  __builtin_amdgcn_s_setprio(0);
  asm volatile("s_waitcnt vmcnt(0) lgkmcnt(0)" ::: "memory");
  __builtin_amdgcn_s_barrier();

  // main: phase t = softmax(t-1) || PV(t-2) || QK(t)
  int sb0 = 2, sb1 = 1, sb2 = 0;
  for (int t = 2; t < NT; t++) {
    VLOAD(t - 2);
    if (t + 1 < NT) KDMA(t + 1, (t + 1) & 1);
    SOFTMAX(sb1, false);
    __builtin_amdgcn_s_setprio(1);
    PV(sb2);
    QK(t & 1, sb0);
    __builtin_amdgcn_s_setprio(0);
    asm volatile("s_waitcnt vmcnt(0) lgkmcnt(0)" ::: "memory");
    __builtin_amdgcn_s_barrier();
    const int tb = sb2; sb2 = sb1; sb1 = sb0; sb0 = tb;
  }

  // phase NT: softmax(NT-1) || PV(NT-2)
  VLOAD(NT - 2);
  SOFTMAX(sb1, true);
  __builtin_amdgcn_s_setprio(1);
  PV(sb2);
  __builtin_amdgcn_s_setprio(0);
  asm volatile("s_waitcnt vmcnt(0) lgkmcnt(0)" ::: "memory");
  __builtin_amdgcn_s_barrier();
  { const int tb = sb2; sb2 = sb1; sb1 = sb0; sb0 = tb; }

  // phase NT+1: PV(NT-1)
  VLOAD(NT - 1);
  __builtin_amdgcn_s_setprio(1);
  PV(sb2);
  __builtin_amdgcn_s_setprio(0);

  __syncthreads();  // all loop LDS traffic done; Ks free for overlays

  float invl[4];
#pragma unroll
  for (int nt = 0; nt < 4; nt++) invl[nt] = 1.0f / lst[nt * 16 + llo];

  // O[n][c] bf16 -> overlay on Ks[0]
  uint16_t(*Old)[CC] = (uint16_t(*)[CC]) & Ks[0][0][0];
#pragma unroll
  for (int rt = 0; rt < 4; rt++)
#pragma unroll
    for (int nt = 0; nt < 4; nt++) {
      ushort4 o4;
      o4.x = f2bf(acc[rt][nt][0] * invl[nt]);
      o4.y = f2bf(acc[rt][nt][1] * invl[nt]);
      o4.z = f2bf(acc[rt][nt][2] * invl[nt]);
      o4.w = f2bf(acc[rt][nt][3] * invl[nt]);
      const int gch = wid * 8 + rt * 2 + (lhi >> 1);
      *(ushort4*)(&Old[nt * 16 + llo][0] + ((gch ^ r7) << 3) + ((lhi & 1) << 2)) = o4;
    }

  // FFN: hidden in 4 d-quarters through Hs (overlay on Ks[1])
  uint16_t(*Hs)[CC] = (uint16_t(*)[CC]) & Ks[1][0][0];
  f32x4 facc[4][4];
#pragma unroll
  for (int i = 0; i < 4; i++)
#pragma unroll
    for (int j = 0; j < 4; j++) facc[i][j] = vzero;
  const float g = gma[0];
  const uint16_t* orow[4];
  const uint16_t* hrow[4];
#pragma unroll
  for (int nt = 0; nt < 4; nt++) {
    orow[nt] = &Old[nt * 16 + llo][0];
    hrow[nt] = &Hs[nt * 16 + llo][0];
  }

  for (int qtr = 0; qtr < 4; qtr++) {
    const int dq0 = qtr * 512;
    f32x4 hacc[4][4];
#pragma unroll
    for (int i = 0; i < 4; i++)
#pragma unroll
      for (int j = 0; j < 4; j++) hacc[i][j] = vzero;
    __syncthreads();  // prev quarter's Hs reads done; O-writes visible (qtr 0)
    __builtin_amdgcn_s_setprio(1);
#pragma unroll 2
    for (int kc8 = 0; kc8 < 64; kc8 += 4) {
      bf8 bo[4], aw[4];
      const int gof = ((kc8 + lhi) ^ r7) << 3;
#pragma unroll
      for (int nt = 0; nt < 4; nt++) bo[nt] = *(const bf8*)(orow[nt] + gof);
#pragma unroll
      for (int dt = 0; dt < 4; dt++) {
        const int d = dq0 + wid * 64 + dt * 16 + llo;
        aw[dt] = *(const bf8*)(W1b + (size_t)d * CC + (kc8 + lhi) * 8);
      }
#pragma unroll
      for (int dt = 0; dt < 4; dt++)
#pragma unroll
        for (int nt = 0; nt < 4; nt++)
          hacc[dt][nt] = __builtin_amdgcn_mfma_f32_16x16x32_bf16(aw[dt], bo[nt], hacc[dt][nt], 0, 0, 0);
    }
    __builtin_amdgcn_s_setprio(0);
#pragma unroll
    for (int dt = 0; dt < 4; dt++) {
      const int dg = dq0 + wid * 64 + dt * 16 + lhi * 4;
      const float4 b1v = *(const float4*)(b1v_ + dg);
#pragma unroll
      for (int nt = 0; nt < 4; nt++) {
        ushort4 h4;
        h4.x = f2bf(fmaxf(hacc[dt][nt][0] + b1v.x, 0.f));
        h4.y = f2bf(fmaxf(hacc[dt][nt][1] + b1v.y, 0.f));
        h4.z = f2bf(fmaxf(hacc[dt][nt][2] + b1v.z, 0.f));
        h4.w = f2bf(fmaxf(hacc[dt][nt][3] + b1v.w, 0.f));
        const int gch = wid * 8 + dt * 2 + (lhi >> 1);
        *(ushort4*)(&Hs[nt * 16 + llo][0] + ((gch ^ r7) << 3) + ((lhi & 1) << 2)) = h4;
      }
    }
    __syncthreads();  // hidden quarter ready
    __builtin_amdgcn_s_setprio(1);
#pragma unroll 2
    for (int kd8 = 0; kd8 < 64; kd8 += 4) {
      bf8 ah[4], bw[4];
      const int gof = ((kd8 + lhi) ^ r7) << 3;
#pragma unroll
      for (int nt = 0; nt < 4; nt++) ah[nt] = *(const bf8*)(hrow[nt] + gof);
#pragma unroll
      for (int ct = 0; ct < 4; ct++) {
        const int c = wid * 64 + ct * 16 + llo;
        bw[ct] = *(const bf8*)(W2b + (size_t)c * D4 + dq0 + (kd8 + lhi) * 8);
      }
#pragma unroll
      for (int nt = 0; nt < 4; nt++)
#pragma unroll
        for (int ct = 0; ct < 4; ct++)
          facc[nt][ct] = __builtin_amdgcn_mfma_f32_16x16x32_bf16(ah[nt], bw[ct], facc[nt][ct], 0, 0, 0);
    }
    __builtin_amdgcn_s_setprio(0);
  }

  // epilogue: out[b,c,n] = (facc + b2[c])*gamma + query  (float4 along n)
#pragma unroll
  for (int nt = 0; nt < 4; nt++) {
    const int n = n0 + nt * 16 + lhi * 4;
#pragma unroll
    for (int ct = 0; ct < 4; ct++) {
      const int c = wid * 64 + ct * 16 + llo;
      const float b2c = b2[c];
      const size_t off = ((size_t)b * CC + c) * NN + n;
      const float4 q4 = *(const float4*)(qry + off);
      float4 o4;
      o4.x = (facc[nt][ct][0] + b2c) * g + q4.x;
      o4.y = (facc[nt][ct][1] + b2c) * g + q4.y;
      o4.z = (facc[nt][ct][2] + b2c) * g + q4.z;
      o4.w = (facc[nt][ct][3] + b2c) * g + q4.w;
      *(float4*)(out + off) = o4;
    }
  }
}

extern "C" void kernel_launch(void* const* d_in, const int* in_sizes, int n_in,
                              void* d_out, int out_size, void* d_ws, size_t ws_size,
                              hipStream_t stream) {
  const float* q = (const float*)d_in[0];
  const float* k = (const float*)d_in[1];
  const float* v = (const float*)d_in[2];
  const float* w1 = (const float*)d_in[3];
  const float* b1 = (const float*)d_in[4];
  const float* w2 = (const float*)d_in[5];
  const float* b2 = (const float*)d_in[6];
  const float* gm = (const float*)d_in[7];
  float* out = (float*)d_out;

  uint16_t* Qt = (uint16_t*)d_ws;                    // [B][N][C] bf16 (pre-scaled)
  uint16_t* Kt = Qt + (size_t)BB * NN * CC;          // [B][N][C] bf16
  uint16_t* Vp = Kt + (size_t)BB * NN * CC;          // fragment-packed V bf16 (32 MB)
  uint16_t* W1b = Vp + (size_t)BB * NN * CC;         // [2048][512] bf16
  uint16_t* W2b = W1b + (size_t)D4 * CC;             // [512][2048] bf16

  dim3 tgrid(NN / 32, CC / 32, BB);
  transpose_cast_k<<<tgrid, 256, 0, stream>>>(q, Qt, 0.044194173824159216f);
  transpose_cast_k<<<tgrid, 256, 0, stream>>>(k, Kt, 1.0f);
  vpack_k<<<BB * NT * 8, 256, 0, stream>>>(v, Vp);
  cast_k<<<(D4 * CC / 4 + 255) / 256, 256, 0, stream>>>(w1, W1b, D4 * CC);
  cast_k<<<(CC * D4 / 4 + 255) / 256, 256, 0, stream>>>(w2, W2b, CC * D4);
  attn_ffn_k<<<dim3(NN / QB, BB), 512, 0, stream>>>(Qt, Kt, Vp, W1b, W2b, b1, b2, gm, q, out);
}

// Round 19
// 688.314 us; speedup vs baseline: 1.0543x; 1.0242x over previous
//
#include <hip/hip_runtime.h>
#include <hip/hip_bf16.h>
#include <stdint.h>

#define BB 8
#define CC 512
#define NN 4096
#define QB 64
#define KB 64
#define D4 2048
#define NT (NN / KB)
#define SPAD 80  // SP row stride (u16): 160 B -> uniform b128 bank starts (R18-measured best)

typedef short bf8 __attribute__((ext_vector_type(8)));
typedef float f32x4 __attribute__((ext_vector_type(4)));

__device__ __forceinline__ uint16_t f2bf(float f) {
  uint32_t u = __builtin_bit_cast(uint32_t, f);
  u = (u + 0x7FFFu + ((u >> 16) & 1u)) >> 16;
  return (uint16_t)u;
}
__device__ __forceinline__ float bf2f(uint16_t u) {
  return __builtin_bit_cast(float, (uint32_t)u << 16);
}

__device__ __forceinline__ void gl_lds16(const void* g, void* l) {
  __builtin_amdgcn_global_load_lds((__attribute__((address_space(1))) void*)g,
                                   (__attribute__((address_space(3))) void*)l, 16, 0, 0);
}

// [B,C,N] fp32 -> [B,N,C] bf16 (used for K only now)
__global__ __launch_bounds__(256) void transpose_cast_k(const float* __restrict__ src,
                                                        uint16_t* __restrict__ dst,
                                                        float scale) {
  __shared__ float tile[32][33];
  int b = blockIdx.z;
  int n0 = blockIdx.x * 32, c0 = blockIdx.y * 32;
  int tx = threadIdx.x & 31, ty = threadIdx.x >> 5;
  const float* s = src + ((size_t)b * CC + c0) * NN + n0;
#pragma unroll
  for (int i = 0; i < 4; i++) {
    int c = ty + i * 8;
    tile[tx][c] = s[(size_t)c * NN + tx];
  }
  __syncthreads();
  uint16_t* d = dst + ((size_t)b * NN + n0) * CC + c0;
#pragma unroll
  for (int i = 0; i < 4; i++) {
    int n = ty + i * 8;
    d[(size_t)n * CC + tx] = f2bf(tile[n][tx] * scale);
  }
}

__global__ __launch_bounds__(256) void cast_k(const float* __restrict__ in,
                                              uint16_t* __restrict__ out, int n) {
  int i = (blockIdx.x * 256 + threadIdx.x) * 4;
  if (i >= n) return;
  float4 v = *(const float4*)(in + i);
  ushort4 o;
  o.x = f2bf(v.x); o.y = f2bf(v.y); o.z = f2bf(v.z); o.w = f2bf(v.w);
  *(ushort4*)(out + i) = o;
}

// Pack V [B,C,N] fp32 -> fragment-ordered bf16 (R13-proven): chunk
// (((b*NT+t)*8+w)*2+ks)*4+rt is 1 KB = 64 lanes x 16 B, fully coalesced.
__global__ __launch_bounds__(256) void vpack_k(const float* __restrict__ v,
                                               uint16_t* __restrict__ vp) {
  const int blk = blockIdx.x;             // (b*NT+mt)*8 + w
  const int w = blk & 7, mtb = blk >> 3;
  const int mt = mtb & (NT - 1), b = mtb >> 6;
  const int tid = threadIdx.x;
#pragma unroll
  for (int h = 0; h < 2; h++) {
    const int c = tid + h * 256;          // ks*256+rt*64+l
    const int ks = c >> 8, rt = (c >> 6) & 3, l = c & 63;
    const int llo = l & 15, lhi = l >> 4;
    const float* src = v + ((size_t)b * CC + w * 64 + rt * 16 + llo) * NN + mt * 64 + ks * 32 + lhi * 8;
    const float4 f0 = *(const float4*)src;
    const float4 f1 = *(const float4*)(src + 4);
    ushort4 o0, o1;
    o0.x = f2bf(f0.x); o0.y = f2bf(f0.y); o0.z = f2bf(f0.z); o0.w = f2bf(f0.w);
    o1.x = f2bf(f1.x); o1.y = f2bf(f1.y); o1.z = f2bf(f1.z); o1.w = f2bf(f1.w);
    uint16_t* dst = vp + (size_t)blk * 4096 + ks * 2048 + rt * 512 + l * 8;
    *(ushort4*)dst = o0;
    *(ushort4*)(dst + 4) = o1;
  }
}

// Fused flash-attention + FFN. Depth-2 pipeline (R15/R18), ONE barrier/iter.
// Q fragments gathered directly from fp32 qry in the prologue (scale folded)
// — no Q transpose prepass, no Qt buffer.
__global__ __launch_bounds__(512) __attribute__((amdgpu_waves_per_eu(2, 2))) void attn_ffn_k(
    const uint16_t* __restrict__ Kt, const uint16_t* __restrict__ Vp,
    const uint16_t* __restrict__ W1b, const uint16_t* __restrict__ W2b,
    const float* __restrict__ b1v_, const float* __restrict__ b2,
    const float* __restrict__ gma, const float* __restrict__ qry,
    float* __restrict__ out) {
  __shared__ __attribute__((aligned(16))) uint16_t Ks[2][KB][CC];   // 128 KB dbuf; FFN overlay
  __shared__ __attribute__((aligned(16))) uint16_t SP[3][QB][SPAD]; // 30 KB: S(bf16)->P in place
  __shared__ float rsc[3][QB];
  __shared__ float lst[QB];  // total 162816 B -> 1 block/CU

  const int bid = blockIdx.x + gridDim.x * blockIdx.y;
  const int b = bid & 7;          // batch == XCD round-robin
  const int n0 = (bid >> 3) * QB;
  const int tid = threadIdx.x;
  const int lane = tid & 63, wid = tid >> 6;
  const int lhi = lane >> 4, llo = lane & 15;
  const int r7 = llo & 7;

  const int srt = wid >> 1;        // S row-tile (q), waves pair up
  const int sct0 = (wid & 1) * 2;  // S col-tiles (k): sct0, sct0+1

  // DMA K(0) -> Ks[0] first (starts flowing under the Q gather)
#pragma unroll
  for (int j = 0; j < 8; j++) {
    const int r = wid * 8 + j;
    gl_lds16(Kt + ((size_t)b * NN + r) * CC + ((lane ^ (r & 7)) << 3), &Ks[0][r][0]);
  }

  // Q fragments <- fp32 qry gather, scale folded into the cast (once per block)
  const float qscale = 0.044194173824159216f;  // 512^-0.5
  bf8 qf[16];
  {
    const int qn = n0 + srt * 16 + llo;
    const float* qb = qry + (size_t)b * CC * NN + qn;
#pragma unroll
    for (int kc = 0; kc < 16; kc++) {
      bf8 f;
#pragma unroll
      for (int e = 0; e < 8; e++) {
        const int c = kc * 32 + lhi * 8 + e;
        f[e] = (short)f2bf(qb[(size_t)c * NN] * qscale);
      }
      qf[kc] = f;
    }
  }

  const f32x4 vzero = {0.f, 0.f, 0.f, 0.f};
  f32x4 acc[4][4];
#pragma unroll
  for (int i = 0; i < 4; i++)
#pragma unroll
    for (int j = 0; j < 4; j++) acc[i][j] = vzero;

  const uint16_t* vpw = Vp + (size_t)b * ((size_t)NT * 8 * 4096) + wid * 4096 + lane * 8;
  const int srow = tid >> 3, sj = tid & 7;  // softmax mapping: 8 threads/row
  float m_run = -__builtin_inff(), l_run = 0.f;
  bf8 av[2][4];

  auto QK = [&](int kbuf, int sb) {
    const uint16_t* k0row = &Ks[kbuf][sct0 * 16 + llo][0];
    const uint16_t* k1row = &Ks[kbuf][sct0 * 16 + 16 + llo][0];
    f32x4 s0 = vzero, s1 = vzero;
#pragma unroll
    for (int kc = 0; kc < 16; kc++) {
      const int g = ((kc * 4 + lhi) ^ r7) << 3;
      bf8 bk0 = *(const bf8*)(k0row + g);
      bf8 bk1 = *(const bf8*)(k1row + g);
      s0 = __builtin_amdgcn_mfma_f32_16x16x32_bf16(qf[kc], bk0, s0, 0, 0, 0);
      s1 = __builtin_amdgcn_mfma_f32_16x16x32_bf16(qf[kc], bk1, s1, 0, 0, 0);
    }
    const int n = srt * 16 + lhi * 4;
#pragma unroll
    for (int r = 0; r < 4; r++) {
      SP[sb][n + r][sct0 * 16 + llo] = f2bf(s0[r]);
      SP[sb][n + r][sct0 * 16 + 16 + llo] = f2bf(s1[r]);
    }
  };

  auto SOFTMAX = [&](int sb, bool last) {
    const bf8 sv8 = *(const bf8*)&SP[sb][srow][sj * 8];
    float sv[8];
#pragma unroll
    for (int k2 = 0; k2 < 8; k2++) sv[k2] = bf2f((uint16_t)sv8[k2]);
    float mx = fmaxf(fmaxf(fmaxf(sv[0], sv[1]), fmaxf(sv[2], sv[3])),
                     fmaxf(fmaxf(sv[4], sv[5]), fmaxf(sv[6], sv[7])));
    mx = fmaxf(mx, __shfl_xor(mx, 1, 8));
    mx = fmaxf(mx, __shfl_xor(mx, 2, 8));
    mx = fmaxf(mx, __shfl_xor(mx, 4, 8));
    const float nm = fmaxf(m_run, mx);
    const float rs = __expf(m_run - nm);
    float p[8], psum = 0.f;
#pragma unroll
    for (int k2 = 0; k2 < 8; k2++) {
      p[k2] = __expf(sv[k2] - nm);
      psum += p[k2];
    }
    bf8 pk;
#pragma unroll
    for (int k2 = 0; k2 < 8; k2++) pk[k2] = (short)f2bf(p[k2]);
    *(bf8*)&SP[sb][srow][sj * 8] = pk;  // in-place S->P (R6/R9-validated)
    psum += __shfl_xor(psum, 1, 8);
    psum += __shfl_xor(psum, 2, 8);
    psum += __shfl_xor(psum, 4, 8);
    l_run = l_run * rs + psum;
    m_run = nm;
    if (sj == 0) {
      rsc[sb][srow] = rs;
      if (last) lst[srow] = l_run;
    }
  };

  auto PV = [&](int sb) {
    float rsn[4];
#pragma unroll
    for (int nt = 0; nt < 4; nt++) rsn[nt] = rsc[sb][nt * 16 + llo];
#pragma unroll
    for (int rt = 0; rt < 4; rt++)
#pragma unroll
      for (int nt = 0; nt < 4; nt++) acc[rt][nt] *= rsn[nt];
#pragma unroll
    for (int ks = 0; ks < 2; ks++) {
      bf8 bp[4];
#pragma unroll
      for (int nt = 0; nt < 4; nt++)
        bp[nt] = *(const bf8*)&SP[sb][nt * 16 + llo][(ks * 4 + lhi) * 8];
#pragma unroll
      for (int rt = 0; rt < 4; rt++)
#pragma unroll
        for (int nt = 0; nt < 4; nt++)
          acc[rt][nt] = __builtin_amdgcn_mfma_f32_16x16x32_bf16(av[ks][rt], bp[nt], acc[rt][nt], 0, 0, 0);
    }
  };

  auto VLOAD = [&](int t) {
    const uint16_t* vt = vpw + (size_t)t * 32768;
#pragma unroll
    for (int ks = 0; ks < 2; ks++)
#pragma unroll
      for (int rt = 0; rt < 4; rt++)
        av[ks][rt] = *(const bf8*)(vt + ks * 2048 + rt * 512);
  };

  auto KDMA = [&](int t, int buf) {
#pragma unroll
    for (int j = 0; j < 8; j++) {
      const int r = wid * 8 + j;
      gl_lds16(Kt + ((size_t)b * NN + t * KB + r) * CC + ((lane ^ (r & 7)) << 3),
               &Ks[buf][r][0]);
    }
  };

  // ---------- depth-2 pipeline, one barrier per phase ----------
  asm volatile("s_waitcnt vmcnt(0)" ::: "memory");
  __builtin_amdgcn_s_barrier();

  // phase 0: QK(0)
  KDMA(1, 1);
  __builtin_amdgcn_s_setprio(1);
  QK(0, 0);
  __builtin_amdgcn_s_setprio(0);
  asm volatile("s_waitcnt vmcnt(0) lgkmcnt(0)" ::: "memory");
  __builtin_amdgcn_s_barrier();

  // phase 1: softmax(0) || QK(1)
  KDMA(2, 0);
  SOFTMAX(0, false);
  __builtin_amdgcn_s_setprio(1);
  QK(1, 1);
  __builtin_amdgcn_s_setprio(0);
  asm volatile("s_waitcnt vmcnt(0) lgkmcnt(0)" ::: "memory");
  __builtin_amdgcn_s_barrier();

  // main: phase t = softmax(t-1) || PV(t-2) || QK(t)
  int sb0 = 2, sb1 = 1, sb2 = 0;
  for (int t = 2; t < NT; t++) {
    VLOAD(t - 2);
    if (t + 1 < NT) KDMA(t + 1, (t + 1) & 1);
    SOFTMAX(sb1, false);
    __builtin_amdgcn_s_setprio(1);
    PV(sb2);
    QK(t & 1, sb0);
    __builtin_amdgcn_s_setprio(0);
    asm volatile("s_waitcnt vmcnt(0) lgkmcnt(0)" ::: "memory");
    __builtin_amdgcn_s_barrier();
    const int tb = sb2; sb2 = sb1; sb1 = sb0; sb0 = tb;
  }

  // phase NT: softmax(NT-1) || PV(NT-2)
  VLOAD(NT - 2);
  SOFTMAX(sb1, true);
  __builtin_amdgcn_s_setprio(1);
  PV(sb2);
  __builtin_amdgcn_s_setprio(0);
  asm volatile("s_waitcnt vmcnt(0) lgkmcnt(0)" ::: "memory");
  __builtin_amdgcn_s_barrier();
  { const int tb = sb2; sb2 = sb1; sb1 = sb0; sb0 = tb; }

  // phase NT+1: PV(NT-1)
  VLOAD(NT - 1);
  __builtin_amdgcn_s_setprio(1);
  PV(sb2);
  __builtin_amdgcn_s_setprio(0);

  __syncthreads();  // all loop LDS traffic done; Ks free for overlays

  float invl[4];
#pragma unroll
  for (int nt = 0; nt < 4; nt++) invl[nt] = 1.0f / lst[nt * 16 + llo];

  // O[n][c] bf16 -> overlay on Ks[0]
  uint16_t(*Old)[CC] = (uint16_t(*)[CC]) & Ks[0][0][0];
#pragma unroll
  for (int rt = 0; rt < 4; rt++)
#pragma unroll
    for (int nt = 0; nt < 4; nt++) {
      ushort4 o4;
      o4.x = f2bf(acc[rt][nt][0] * invl[nt]);
      o4.y = f2bf(acc[rt][nt][1] * invl[nt]);
      o4.z = f2bf(acc[rt][nt][2] * invl[nt]);
      o4.w = f2bf(acc[rt][nt][3] * invl[nt]);
      const int gch = wid * 8 + rt * 2 + (lhi >> 1);
      *(ushort4*)(&Old[nt * 16 + llo][0] + ((gch ^ r7) << 3) + ((lhi & 1) << 2)) = o4;
    }

  // FFN: hidden in 4 d-quarters through Hs (overlay on Ks[1])
  uint16_t(*Hs)[CC] = (uint16_t(*)[CC]) & Ks[1][0][0];
  f32x4 facc[4][4];
#pragma unroll
  for (int i = 0; i < 4; i++)
#pragma unroll
    for (int j = 0; j < 4; j++) facc[i][j] = vzero;
  const float g = gma[0];
  const uint16_t* orow[4];
  const uint16_t* hrow[4];
#pragma unroll
  for (int nt = 0; nt < 4; nt++) {
    orow[nt] = &Old[nt * 16 + llo][0];
    hrow[nt] = &Hs[nt * 16 + llo][0];
  }

  for (int qtr = 0; qtr < 4; qtr++) {
    const int dq0 = qtr * 512;
    f32x4 hacc[4][4];
#pragma unroll
    for (int i = 0; i < 4; i++)
#pragma unroll
      for (int j = 0; j < 4; j++) hacc[i][j] = vzero;
    __syncthreads();  // prev quarter's Hs reads done; O-writes visible (qtr 0)
    __builtin_amdgcn_s_setprio(1);
#pragma unroll 2
    for (int kc8 = 0; kc8 < 64; kc8 += 4) {
      bf8 bo[4], aw[4];
      const int gof = ((kc8 + lhi) ^ r7) << 3;
#pragma unroll
      for (int nt = 0; nt < 4; nt++) bo[nt] = *(const bf8*)(orow[nt] + gof);
#pragma unroll
      for (int dt = 0; dt < 4; dt++) {
        const int d = dq0 + wid * 64 + dt * 16 + llo;
        aw[dt] = *(const bf8*)(W1b + (size_t)d * CC + (kc8 + lhi) * 8);
      }
#pragma unroll
      for (int dt = 0; dt < 4; dt++)
#pragma unroll
        for (int nt = 0; nt < 4; nt++)
          hacc[dt][nt] = __builtin_amdgcn_mfma_f32_16x16x32_bf16(aw[dt], bo[nt], hacc[dt][nt], 0, 0, 0);
    }
    __builtin_amdgcn_s_setprio(0);
#pragma unroll
    for (int dt = 0; dt < 4; dt++) {
      const int dg = dq0 + wid * 64 + dt * 16 + lhi * 4;
      const float4 b1v = *(const float4*)(b1v_ + dg);
#pragma unroll
      for (int nt = 0; nt < 4; nt++) {
        ushort4 h4;
        h4.x = f2bf(fmaxf(hacc[dt][nt][0] + b1v.x, 0.f));
        h4.y = f2bf(fmaxf(hacc[dt][nt][1] + b1v.y, 0.f));
        h4.z = f2bf(fmaxf(hacc[dt][nt][2] + b1v.z, 0.f));
        h4.w = f2bf(fmaxf(hacc[dt][nt][3] + b1v.w, 0.f));
        const int gch = wid * 8 + dt * 2 + (lhi >> 1);
        *(ushort4*)(&Hs[nt * 16 + llo][0] + ((gch ^ r7) << 3) + ((lhi & 1) << 2)) = h4;
      }
    }
    __syncthreads();  // hidden quarter ready
    __builtin_amdgcn_s_setprio(1);
#pragma unroll 2
    for (int kd8 = 0; kd8 < 64; kd8 += 4) {
      bf8 ah[4], bw[4];
      const int gof = ((kd8 + lhi) ^ r7) << 3;
#pragma unroll
      for (int nt = 0; nt < 4; nt++) ah[nt] = *(const bf8*)(hrow[nt] + gof);
#pragma unroll
      for (int ct = 0; ct < 4; ct++) {
        const int c = wid * 64 + ct * 16 + llo;
        bw[ct] = *(const bf8*)(W2b + (size_t)c * D4 + dq0 + (kd8 + lhi) * 8);
      }
#pragma unroll
      for (int nt = 0; nt < 4; nt++)
#pragma unroll
        for (int ct = 0; ct < 4; ct++)
          facc[nt][ct] = __builtin_amdgcn_mfma_f32_16x16x32_bf16(ah[nt], bw[ct], facc[nt][ct], 0, 0, 0);
    }
    __builtin_amdgcn_s_setprio(0);
  }

  // epilogue: out[b,c,n] = (facc + b2[c])*gamma + query  (float4 along n)
#pragma unroll
  for (int nt = 0; nt < 4; nt++) {
    const int n = n0 + nt * 16 + lhi * 4;
#pragma unroll
    for (int ct = 0; ct < 4; ct++) {
      const int c = wid * 64 + ct * 16 + llo;
      const float b2c = b2[c];
      const size_t off = ((size_t)b * CC + c) * NN + n;
      const float4 q4 = *(const float4*)(qry + off);
      float4 o4;
      o4.x = (facc[nt][ct][0] + b2c) * g + q4.x;
      o4.y = (facc[nt][ct][1] + b2c) * g + q4.y;
      o4.z = (facc[nt][ct][2] + b2c) * g + q4.z;
      o4.w = (facc[nt][ct][3] + b2c) * g + q4.w;
      *(float4*)(out + off) = o4;
    }
  }
}

extern "C" void kernel_launch(void* const* d_in, const int* in_sizes, int n_in,
                              void* d_out, int out_size, void* d_ws, size_t ws_size,
                              hipStream_t stream) {
  const float* q = (const float*)d_in[0];
  const float* k = (const float*)d_in[1];
  const float* v = (const float*)d_in[2];
  const float* w1 = (const float*)d_in[3];
  const float* b1 = (const float*)d_in[4];
  const float* w2 = (const float*)d_in[5];
  const float* b2 = (const float*)d_in[6];
  const float* gm = (const float*)d_in[7];
  float* out = (float*)d_out;

  uint16_t* Kt = (uint16_t*)d_ws;                    // [B][N][C] bf16              32 MB
  uint16_t* Vp = Kt + (size_t)BB * NN * CC;          // fragment-packed V bf16      32 MB
  uint16_t* W1b = Vp + (size_t)BB * NN * CC;         // [2048][512] bf16             2 MB
  uint16_t* W2b = W1b + (size_t)D4 * CC;             // [512][2048] bf16             2 MB

  dim3 tgrid(NN / 32, CC / 32, BB);
  transpose_cast_k<<<tgrid, 256, 0, stream>>>(k, Kt, 1.0f);
  vpack_k<<<BB * NT * 8, 256, 0, stream>>>(v, Vp);
  cast_k<<<(D4 * CC / 4 + 255) / 256, 256, 0, stream>>>(w1, W1b, D4 * CC);
  cast_k<<<(CC * D4 / 4 + 255) / 256, 256, 0, stream>>>(w2, W2b, CC * D4);
  attn_ffn_k<<<dim3(NN / QB, BB), 512, 0, stream>>>(Kt, Vp, W1b, W2b, b1, b2, gm, q, out);
}

// Round 20
// 637.671 us; speedup vs baseline: 1.1380x; 1.0794x over previous
//
#include <hip/hip_runtime.h>
#include <hip/hip_bf16.h>
#include <hip/hip_fp8.h>
#include <stdint.h>

#define BB 8
#define CC 512
#define NN 4096
#define QB 64
#define KB 64
#define D4 2048
#define NT (NN / KB)
#define SPAD 80

typedef short bf8 __attribute__((ext_vector_type(8)));
typedef float f32x4 __attribute__((ext_vector_type(4)));
typedef unsigned long long u64;

__device__ __forceinline__ uint16_t f2bf(float f) {
  uint32_t u = __builtin_bit_cast(uint32_t, f);
  u = (u + 0x7FFFu + ((u >> 16) & 1u)) >> 16;
  return (uint16_t)u;
}
__device__ __forceinline__ float bf2f(uint16_t u) {
  return __builtin_bit_cast(float, (uint32_t)u << 16);
}
__device__ __forceinline__ uint8_t f2e4m3(float f) {
  __hip_fp8_e4m3 t(f);
  return (uint8_t)t.__x;
}

__device__ __forceinline__ void gl_lds16(const void* g, void* l) {
  __builtin_amdgcn_global_load_lds((__attribute__((address_space(1))) void*)g,
                                   (__attribute__((address_space(3))) void*)l, 16, 0, 0);
}

// K: [B,C,N] fp32 -> [B,N,512] fp8 e4m3 (linear layout; swizzle applied at DMA)
__global__ __launch_bounds__(256) void transpose_cast_fp8_k(const float* __restrict__ src,
                                                            uint8_t* __restrict__ dst) {
  __shared__ float tile[32][33];
  int b = blockIdx.z;
  int n0 = blockIdx.x * 32, c0 = blockIdx.y * 32;
  int tx = threadIdx.x & 31, ty = threadIdx.x >> 5;
  const float* s = src + ((size_t)b * CC + c0) * NN + n0;
#pragma unroll
  for (int i = 0; i < 4; i++) {
    int c = ty + i * 8;
    tile[tx][c] = s[(size_t)c * NN + tx];
  }
  __syncthreads();
  uint8_t* d = dst + (((size_t)b * NN + n0) << 9) + c0;
#pragma unroll
  for (int i = 0; i < 4; i++) {
    int n = ty + i * 8;
    d[((size_t)n << 9) + tx] = f2e4m3(tile[n][tx]);
  }
}

__global__ __launch_bounds__(256) void cast_k(const float* __restrict__ in,
                                              uint16_t* __restrict__ out, int n) {
  int i = (blockIdx.x * 256 + threadIdx.x) * 4;
  if (i >= n) return;
  float4 v = *(const float4*)(in + i);
  ushort4 o;
  o.x = f2bf(v.x); o.y = f2bf(v.y); o.z = f2bf(v.z); o.w = f2bf(v.w);
  *(ushort4*)(out + i) = o;
}

// Pack V [B,C,N] fp32 -> fragment-ordered bf16 (R13-proven, coalesced 1 KB chunks)
__global__ __launch_bounds__(256) void vpack_k(const float* __restrict__ v,
                                               uint16_t* __restrict__ vp) {
  const int blk = blockIdx.x;
  const int w = blk & 7, mtb = blk >> 3;
  const int mt = mtb & (NT - 1), b = mtb >> 6;
  const int tid = threadIdx.x;
#pragma unroll
  for (int h = 0; h < 2; h++) {
    const int c = tid + h * 256;
    const int ks = c >> 8, rt = (c >> 6) & 3, l = c & 63;
    const int llo = l & 15, lhi = l >> 4;
    const float* src = v + ((size_t)b * CC + w * 64 + rt * 16 + llo) * NN + mt * 64 + ks * 32 + lhi * 8;
    const float4 f0 = *(const float4*)src;
    const float4 f1 = *(const float4*)(src + 4);
    ushort4 o0, o1;
    o0.x = f2bf(f0.x); o0.y = f2bf(f0.y); o0.z = f2bf(f0.z); o0.w = f2bf(f0.w);
    o1.x = f2bf(f1.x); o1.y = f2bf(f1.y); o1.z = f2bf(f1.z); o1.w = f2bf(f1.w);
    uint16_t* dst = vp + (size_t)blk * 4096 + ks * 2048 + rt * 512 + l * 8;
    *(ushort4*)dst = o0;
    *(ushort4*)(dst + 4) = o1;
  }
}

// Fused flash-attention + FFN. Depth-2 pipeline (R15/R19) with fp8 QK^T:
// K tiles in LDS as fp8 (32 KB/tile), QK via mfma_f32_16x16x32_fp8_fp8 reading
// b64 fragments (halved LDS traffic). V/P/S/FFN stay bf16.
__global__ __launch_bounds__(512) __attribute__((amdgpu_waves_per_eu(2, 2))) void attn_ffn_k(
    const uint8_t* __restrict__ Ktf8, const uint16_t* __restrict__ Vp,
    const uint16_t* __restrict__ W1b, const uint16_t* __restrict__ W2b,
    const float* __restrict__ b1v_, const float* __restrict__ b2,
    const float* __restrict__ gma, const float* __restrict__ qry,
    float* __restrict__ out) {
  // manual overlay: [0,64K) Ks fp8 dbuf | [64K,94K) SP | [94K,95K) rsc
  // post-loop: [0,64K) O tile bf16 | [64K,128K) H tile bf16 | [128K,+) lst
  __shared__ __attribute__((aligned(16))) uint8_t smem[131840];
  uint8_t* KsP = smem;                                            // [2][64][512] fp8
  uint16_t(*SP)[QB][SPAD] = (uint16_t(*)[QB][SPAD])(smem + 65536); // 30720 B
  float* rscP = (float*)(smem + 96256);                            // [3][64]
  float* lstP = (float*)(smem + 131072);                           // [64]

  const int bid = blockIdx.x + gridDim.x * blockIdx.y;
  const int b = bid & 7;          // batch == XCD round-robin
  const int n0 = (bid >> 3) * QB;
  const int tid = threadIdx.x;
  const int lane = tid & 63, wid = tid >> 6;
  const int lhi = lane >> 4, llo = lane & 15;
  const int r7 = llo & 7;

  const int srt = wid >> 1;        // S row-tile (q)
  const int sct0 = (wid & 1) * 2;  // S col-tiles (k): sct0, sct0+1

  auto KDMA = [&](int t, int buf) {
#pragma unroll
    for (int j = 0; j < 4; j++) {
      const int r0 = wid * 8 + j * 2;
      const int rr = r0 + (lane >> 5);
      const int ch = (lane & 31) ^ (rr & 7);  // 16B-chunk swizzle in source
      gl_lds16(Ktf8 + (((size_t)b * NN + (size_t)t * KB + rr) << 9) + (ch << 4),
               KsP + buf * 32768 + r0 * 512);
    }
  };

  // DMA K(0) first (flows under the Q gather)
  KDMA(0, 0);

  // Q fragments <- fp32 qry gather, scale folded, packed to fp8 (once per block)
  const float qscale = 0.044194173824159216f;  // 512^-0.5
  u64 qf8[16];
  {
    const int qn = n0 + srt * 16 + llo;
    const float* qb = qry + (size_t)b * CC * NN + qn;
#pragma unroll
    for (int kc = 0; kc < 16; kc++) {
      u64 v = 0;
#pragma unroll
      for (int e = 0; e < 8; e++) {
        const int c = kc * 32 + lhi * 8 + e;
        v |= (u64)f2e4m3(qb[(size_t)c * NN] * qscale) << (8 * e);
      }
      qf8[kc] = v;
    }
  }

  const f32x4 vzero = {0.f, 0.f, 0.f, 0.f};
  f32x4 acc[4][4];
#pragma unroll
  for (int i = 0; i < 4; i++)
#pragma unroll
    for (int j = 0; j < 4; j++) acc[i][j] = vzero;

  const uint16_t* vpw = Vp + (size_t)b * ((size_t)NT * 8 * 4096) + wid * 4096 + lane * 8;
  const int srow = tid >> 3, sj = tid & 7;  // softmax: 8 threads/row
  float m_run = -__builtin_inff(), l_run = 0.f;
  bf8 av[2][4];

  auto QK = [&](int kbuf, int sb) {
    const uint8_t* k0row = KsP + kbuf * 32768 + (sct0 * 16 + llo) * 512;
    const uint8_t* k1row = k0row + 16 * 512;
    f32x4 s0 = vzero, s1 = vzero;
#pragma unroll
    for (int kc = 0; kc < 16; kc++) {
      const int g8 = kc * 4 + lhi;
      const int off = (((g8 >> 1) ^ r7) << 4) + ((g8 & 1) << 3);
      const long long bk0 = *(const long long*)(k0row + off);
      const long long bk1 = *(const long long*)(k1row + off);
      s0 = __builtin_amdgcn_mfma_f32_16x16x32_fp8_fp8((long long)qf8[kc], bk0, s0, 0, 0, 0);
      s1 = __builtin_amdgcn_mfma_f32_16x16x32_fp8_fp8((long long)qf8[kc], bk1, s1, 0, 0, 0);
    }
    const int n = srt * 16 + lhi * 4;
#pragma unroll
    for (int r = 0; r < 4; r++) {
      SP[sb][n + r][sct0 * 16 + llo] = f2bf(s0[r]);
      SP[sb][n + r][sct0 * 16 + 16 + llo] = f2bf(s1[r]);
    }
  };

  auto SOFTMAX = [&](int sb, bool last) {
    const bf8 sv8 = *(const bf8*)&SP[sb][srow][sj * 8];
    float sv[8];
#pragma unroll
    for (int k2 = 0; k2 < 8; k2++) sv[k2] = bf2f((uint16_t)sv8[k2]);
    float mx = fmaxf(fmaxf(fmaxf(sv[0], sv[1]), fmaxf(sv[2], sv[3])),
                     fmaxf(fmaxf(sv[4], sv[5]), fmaxf(sv[6], sv[7])));
    mx = fmaxf(mx, __shfl_xor(mx, 1, 8));
    mx = fmaxf(mx, __shfl_xor(mx, 2, 8));
    mx = fmaxf(mx, __shfl_xor(mx, 4, 8));
    const float nm = fmaxf(m_run, mx);
    const float rs = __expf(m_run - nm);
    float p[8], psum = 0.f;
#pragma unroll
    for (int k2 = 0; k2 < 8; k2++) {
      p[k2] = __expf(sv[k2] - nm);
      psum += p[k2];
    }
    bf8 pk;
#pragma unroll
    for (int k2 = 0; k2 < 8; k2++) pk[k2] = (short)f2bf(p[k2]);
    *(bf8*)&SP[sb][srow][sj * 8] = pk;  // in-place S->P
    psum += __shfl_xor(psum, 1, 8);
    psum += __shfl_xor(psum, 2, 8);
    psum += __shfl_xor(psum, 4, 8);
    l_run = l_run * rs + psum;
    m_run = nm;
    if (sj == 0) {
      rscP[sb * QB + srow] = rs;
      if (last) lstP[srow] = l_run;
    }
  };

  auto PV = [&](int sb) {
    float rsn[4];
#pragma unroll
    for (int nt = 0; nt < 4; nt++) rsn[nt] = rscP[sb * QB + nt * 16 + llo];
#pragma unroll
    for (int rt = 0; rt < 4; rt++)
#pragma unroll
      for (int nt = 0; nt < 4; nt++) acc[rt][nt] *= rsn[nt];
#pragma unroll
    for (int ks = 0; ks < 2; ks++) {
      bf8 bp[4];
#pragma unroll
      for (int nt = 0; nt < 4; nt++)
        bp[nt] = *(const bf8*)&SP[sb][nt * 16 + llo][(ks * 4 + lhi) * 8];
#pragma unroll
      for (int rt = 0; rt < 4; rt++)
#pragma unroll
        for (int nt = 0; nt < 4; nt++)
          acc[rt][nt] = __builtin_amdgcn_mfma_f32_16x16x32_bf16(av[ks][rt], bp[nt], acc[rt][nt], 0, 0, 0);
    }
  };

  auto VLOAD = [&](int t) {
    const uint16_t* vt = vpw + (size_t)t * 32768;
#pragma unroll
    for (int ks = 0; ks < 2; ks++)
#pragma unroll
      for (int rt = 0; rt < 4; rt++)
        av[ks][rt] = *(const bf8*)(vt + ks * 2048 + rt * 512);
  };

  // ---------- depth-2 pipeline, one barrier per phase ----------
  asm volatile("s_waitcnt vmcnt(0)" ::: "memory");
  __builtin_amdgcn_s_barrier();

  // phase 0: QK(0)
  KDMA(1, 1);
  __builtin_amdgcn_s_setprio(1);
  QK(0, 0);
  __builtin_amdgcn_s_setprio(0);
  asm volatile("s_waitcnt vmcnt(0) lgkmcnt(0)" ::: "memory");
  __builtin_amdgcn_s_barrier();

  // phase 1: softmax(0) || QK(1)
  KDMA(2, 0);
  SOFTMAX(0, false);
  __builtin_amdgcn_s_setprio(1);
  QK(1, 1);
  __builtin_amdgcn_s_setprio(0);
  asm volatile("s_waitcnt vmcnt(0) lgkmcnt(0)" ::: "memory");
  __builtin_amdgcn_s_barrier();

  // main: phase t = softmax(t-1) || PV(t-2) || QK(t)
  int sb0 = 2, sb1 = 1, sb2 = 0;
  for (int t = 2; t < NT; t++) {
    VLOAD(t - 2);
    if (t + 1 < NT) KDMA(t + 1, (t + 1) & 1);
    SOFTMAX(sb1, false);
    __builtin_amdgcn_s_setprio(1);
    PV(sb2);
    QK(t & 1, sb0);
    __builtin_amdgcn_s_setprio(0);
    asm volatile("s_waitcnt vmcnt(0) lgkmcnt(0)" ::: "memory");
    __builtin_amdgcn_s_barrier();
    const int tb = sb2; sb2 = sb1; sb1 = sb0; sb0 = tb;
  }

  // phase NT: softmax(NT-1) || PV(NT-2)
  VLOAD(NT - 2);
  SOFTMAX(sb1, true);
  __builtin_amdgcn_s_setprio(1);
  PV(sb2);
  __builtin_amdgcn_s_setprio(0);
  asm volatile("s_waitcnt vmcnt(0) lgkmcnt(0)" ::: "memory");
  __builtin_amdgcn_s_barrier();
  { const int tb = sb2; sb2 = sb1; sb1 = sb0; sb0 = tb; }

  // phase NT+1: PV(NT-1)
  VLOAD(NT - 1);
  __builtin_amdgcn_s_setprio(1);
  PV(sb2);
  __builtin_amdgcn_s_setprio(0);

  __syncthreads();  // all loop LDS traffic done; smem free for overlays

  float invl[4];
#pragma unroll
  for (int nt = 0; nt < 4; nt++) invl[nt] = 1.0f / lstP[nt * 16 + llo];

  // O[n][c] bf16 -> overlay at smem[0..64K)
  uint16_t(*Old)[CC] = (uint16_t(*)[CC])smem;
#pragma unroll
  for (int rt = 0; rt < 4; rt++)
#pragma unroll
    for (int nt = 0; nt < 4; nt++) {
      ushort4 o4;
      o4.x = f2bf(acc[rt][nt][0] * invl[nt]);
      o4.y = f2bf(acc[rt][nt][1] * invl[nt]);
      o4.z = f2bf(acc[rt][nt][2] * invl[nt]);
      o4.w = f2bf(acc[rt][nt][3] * invl[nt]);
      const int gch = wid * 8 + rt * 2 + (lhi >> 1);
      *(ushort4*)(&Old[nt * 16 + llo][0] + ((gch ^ r7) << 3) + ((lhi & 1) << 2)) = o4;
    }

  // FFN: hidden in 4 d-quarters through Hs overlay at smem[64K..128K)
  uint16_t(*Hs)[CC] = (uint16_t(*)[CC])(smem + 65536);
  f32x4 facc[4][4];
#pragma unroll
  for (int i = 0; i < 4; i++)
#pragma unroll
    for (int j = 0; j < 4; j++) facc[i][j] = vzero;
  const float g = gma[0];
  const uint16_t* orow[4];
  const uint16_t* hrow[4];
#pragma unroll
  for (int nt = 0; nt < 4; nt++) {
    orow[nt] = &Old[nt * 16 + llo][0];
    hrow[nt] = &Hs[nt * 16 + llo][0];
  }

  for (int qtr = 0; qtr < 4; qtr++) {
    const int dq0 = qtr * 512;
    f32x4 hacc[4][4];
#pragma unroll
    for (int i = 0; i < 4; i++)
#pragma unroll
      for (int j = 0; j < 4; j++) hacc[i][j] = vzero;
    __syncthreads();  // prev quarter's Hs reads done; O-writes visible (qtr 0)
    __builtin_amdgcn_s_setprio(1);
#pragma unroll 2
    for (int kc8 = 0; kc8 < 64; kc8 += 4) {
      bf8 bo[4], aw[4];
      const int gof = ((kc8 + lhi) ^ r7) << 3;
#pragma unroll
      for (int nt = 0; nt < 4; nt++) bo[nt] = *(const bf8*)(orow[nt] + gof);
#pragma unroll
      for (int dt = 0; dt < 4; dt++) {
        const int d = dq0 + wid * 64 + dt * 16 + llo;
        aw[dt] = *(const bf8*)(W1b + (size_t)d * CC + (kc8 + lhi) * 8);
      }
#pragma unroll
      for (int dt = 0; dt < 4; dt++)
#pragma unroll
        for (int nt = 0; nt < 4; nt++)
          hacc[dt][nt] = __builtin_amdgcn_mfma_f32_16x16x32_bf16(aw[dt], bo[nt], hacc[dt][nt], 0, 0, 0);
    }
    __builtin_amdgcn_s_setprio(0);
#pragma unroll
    for (int dt = 0; dt < 4; dt++) {
      const int dg = dq0 + wid * 64 + dt * 16 + lhi * 4;
      const float4 b1v = *(const float4*)(b1v_ + dg);
#pragma unroll
      for (int nt = 0; nt < 4; nt++) {
        ushort4 h4;
        h4.x = f2bf(fmaxf(hacc[dt][nt][0] + b1v.x, 0.f));
        h4.y = f2bf(fmaxf(hacc[dt][nt][1] + b1v.y, 0.f));
        h4.z = f2bf(fmaxf(hacc[dt][nt][2] + b1v.z, 0.f));
        h4.w = f2bf(fmaxf(hacc[dt][nt][3] + b1v.w, 0.f));
        const int gch = wid * 8 + dt * 2 + (lhi >> 1);
        *(ushort4*)(&Hs[nt * 16 + llo][0] + ((gch ^ r7) << 3) + ((lhi & 1) << 2)) = h4;
      }
    }
    __syncthreads();  // hidden quarter ready
    __builtin_amdgcn_s_setprio(1);
#pragma unroll 2
    for (int kd8 = 0; kd8 < 64; kd8 += 4) {
      bf8 ah[4], bw[4];
      const int gof = ((kd8 + lhi) ^ r7) << 3;
#pragma unroll
      for (int nt = 0; nt < 4; nt++) ah[nt] = *(const bf8*)(hrow[nt] + gof);
#pragma unroll
      for (int ct = 0; ct < 4; ct++) {
        const int c = wid * 64 + ct * 16 + llo;
        bw[ct] = *(const bf8*)(W2b + (size_t)c * D4 + dq0 + (kd8 + lhi) * 8);
      }
#pragma unroll
      for (int nt = 0; nt < 4; nt++)
#pragma unroll
        for (int ct = 0; ct < 4; ct++)
          facc[nt][ct] = __builtin_amdgcn_mfma_f32_16x16x32_bf16(ah[nt], bw[ct], facc[nt][ct], 0, 0, 0);
    }
    __builtin_amdgcn_s_setprio(0);
  }

  // epilogue: out[b,c,n] = (facc + b2[c])*gamma + query  (float4 along n)
#pragma unroll
  for (int nt = 0; nt < 4; nt++) {
    const int n = n0 + nt * 16 + lhi * 4;
#pragma unroll
    for (int ct = 0; ct < 4; ct++) {
      const int c = wid * 64 + ct * 16 + llo;
      const float b2c = b2[c];
      const size_t off = ((size_t)b * CC + c) * NN + n;
      const float4 q4 = *(const float4*)(qry + off);
      float4 o4;
      o4.x = (facc[nt][ct][0] + b2c) * g + q4.x;
      o4.y = (facc[nt][ct][1] + b2c) * g + q4.y;
      o4.z = (facc[nt][ct][2] + b2c) * g + q4.z;
      o4.w = (facc[nt][ct][3] + b2c) * g + q4.w;
      *(float4*)(out + off) = o4;
    }
  }
}

extern "C" void kernel_launch(void* const* d_in, const int* in_sizes, int n_in,
                              void* d_out, int out_size, void* d_ws, size_t ws_size,
                              hipStream_t stream) {
  const float* q = (const float*)d_in[0];
  const float* k = (const float*)d_in[1];
  const float* v = (const float*)d_in[2];
  const float* w1 = (const float*)d_in[3];
  const float* b1 = (const float*)d_in[4];
  const float* w2 = (const float*)d_in[5];
  const float* b2 = (const float*)d_in[6];
  const float* gm = (const float*)d_in[7];
  float* out = (float*)d_out;

  uint8_t* Ktf8 = (uint8_t*)d_ws;                          // [B][N][512] fp8   16 MB
  uint16_t* Vp = (uint16_t*)(Ktf8 + (size_t)BB * NN * 512); // packed V bf16    32 MB
  uint16_t* W1b = Vp + (size_t)BB * NN * CC;               // [2048][512] bf16   2 MB
  uint16_t* W2b = W1b + (size_t)D4 * CC;                   // [512][2048] bf16   2 MB

  dim3 tgrid(NN / 32, CC / 32, BB);
  transpose_cast_fp8_k<<<tgrid, 256, 0, stream>>>(k, Ktf8);
  vpack_k<<<BB * NT * 8, 256, 0, stream>>>(v, Vp);
  cast_k<<<(D4 * CC / 4 + 255) / 256, 256, 0, stream>>>(w1, W1b, D4 * CC);
  cast_k<<<(CC * D4 / 4 + 255) / 256, 256, 0, stream>>>(w2, W2b, CC * D4);
  attn_ffn_k<<<dim3(NN / QB, BB), 512, 0, stream>>>(Ktf8, Vp, W1b, W2b, b1, b2, gm, q, out);
}